// Round 5
// baseline (284.002 us; speedup 1.0000x reference)
//
#include <hip/hip_runtime.h>

typedef __bf16 bf16x8 __attribute__((ext_vector_type(8)));
typedef float f32x4 __attribute__((ext_vector_type(4)));

#define T_TOK 1024
#define DIN   2048
#define NH    32
#define NKV   8
#define HD    64
#define NSPLIT 4

__device__ __forceinline__ unsigned short f2bf(float f) {
  unsigned int u = __float_as_uint(f);
  unsigned int r = (u + 0x7fffu + ((u >> 16) & 1u)) >> 16;
  return (unsigned short)r;
}

__device__ __forceinline__ float bf2f(unsigned short u) {
  return __uint_as_float((unsigned int)u << 16);
}

__device__ __forceinline__ void glds16(const void* g, void* lds) {
  __builtin_amdgcn_global_load_lds(
      (const __attribute__((address_space(1))) void*)g,
      (__attribute__((address_space(3))) void*)lds, 16, 0, 0);
}

// ------------- fused fp32 -> bf16 convert for all 5 operands, 1 launch -------
__global__ __launch_bounds__(256) void k_cvt_all(
    const float* __restrict__ x,  const float* __restrict__ wq,
    const float* __restrict__ wk, const float* __restrict__ wv,
    const float* __restrict__ wo, unsigned short* __restrict__ xb,
    unsigned short* __restrict__ wqkv, unsigned short* __restrict__ wob) {
  const long NX = 1l << 21, NWQ = 1l << 22, NWK = 1l << 20, NWV = 1l << 20;
  long i4 = ((long)blockIdx.x * blockDim.x + threadIdx.x) * 4;
  const float* src;
  unsigned short* dst;
  long off;
  if (i4 < NX)                       { src = x;  dst = xb;   off = i4; }
  else if (i4 < NX + NWQ)            { src = wq; dst = wqkv; off = i4 - NX; }
  else if (i4 < NX + NWQ + NWK)      { src = wk; dst = wqkv + NWQ; off = i4 - NX - NWQ; }
  else if (i4 < NX + NWQ + NWK + NWV){ src = wv; dst = wqkv + NWQ + NWK; off = i4 - NX - NWQ - NWK; }
  else                               { src = wo; dst = wob;  off = i4 - NX - NWQ - NWK - NWV; }
  float4 v = *reinterpret_cast<const float4*>(src + off);
  ushort4 o;
  o.x = f2bf(v.x); o.y = f2bf(v.y); o.z = f2bf(v.z); o.w = f2bf(v.w);
  *reinterpret_cast<ushort4*>(dst + off) = o;
}

// ------- bf16 MFMA GEMM, LDS-staged 2-phase: C[M][N] = A[M][K] * B[N][K]^T ---
__global__ __launch_bounds__(256) void k_gemm2(
    const unsigned short* __restrict__ A, const unsigned short* __restrict__ B,
    float* __restrict__ C, int N, int K) {
  __shared__ unsigned short As[2][64 * 64];
  __shared__ unsigned short Bs[2][128 * 64];
  const int lane = threadIdx.x & 63;
  const int wave = threadIdx.x >> 6;
  const int wm = wave >> 1, wn = wave & 1;
  const int lr = lane & 15, lk = lane >> 4;
  const int brow = blockIdx.y * 64;
  const int bcol = blockIdx.x * 128;

  const int srow = lane >> 3;
  const int scol = ((lane & 7) ^ srow) * 8;
  const unsigned short* Ag = A + (long)(brow + srow) * K + scol;
  const unsigned short* Bg = B + (long)(bcol + srow) * K + scol;

  f32x4 acc[2][4];
#pragma unroll
  for (int i = 0; i < 2; i++)
#pragma unroll
    for (int j = 0; j < 4; j++) acc[i][j] = (f32x4){0.f, 0.f, 0.f, 0.f};

  const int swz = (lr & 7) << 4;
  const int nt = K / 64;
  int cur = 0;

#pragma unroll
  for (int i = 0; i < 2; i++) {
    int strip = i * 4 + wave;
    glds16(Ag + (long)strip * 8 * K, (char*)As[0] + strip * 1024);
  }
#pragma unroll
  for (int i = 0; i < 4; i++) {
    int strip = i * 4 + wave;
    glds16(Bg + (long)strip * 8 * K, (char*)Bs[0] + strip * 1024);
  }
  __syncthreads();

  for (int t = 0; t < nt; t++) {
    if (t + 1 < nt) {
      const int kk = (t + 1) * 64;
#pragma unroll
      for (int i = 0; i < 2; i++) {
        int strip = i * 4 + wave;
        glds16(Ag + (long)strip * 8 * K + kk, (char*)As[cur ^ 1] + strip * 1024);
      }
#pragma unroll
      for (int i = 0; i < 4; i++) {
        int strip = i * 4 + wave;
        glds16(Bg + (long)strip * 8 * K + kk, (char*)Bs[cur ^ 1] + strip * 1024);
      }
    }
#pragma unroll
    for (int s = 0; s < 2; s++) {
      bf16x8 a[2], b[4];
#pragma unroll
      for (int i = 0; i < 2; i++) {
        int row = wm * 32 + i * 16 + lr;
        a[i] = *reinterpret_cast<const bf16x8*>(
            (const char*)As[cur] + row * 128 + ((s * 64 + lk * 16) ^ swz));
      }
#pragma unroll
      for (int j = 0; j < 4; j++) {
        int row = wn * 64 + j * 16 + lr;
        b[j] = *reinterpret_cast<const bf16x8*>(
            (const char*)Bs[cur] + row * 128 + ((s * 64 + lk * 16) ^ swz));
      }
#pragma unroll
      for (int i = 0; i < 2; i++)
#pragma unroll
        for (int j = 0; j < 4; j++)
          acc[i][j] = __builtin_amdgcn_mfma_f32_16x16x32_bf16(a[i], b[j], acc[i][j], 0, 0, 0);
    }
    __syncthreads();
    cur ^= 1;
  }

#pragma unroll
  for (int i = 0; i < 2; i++)
#pragma unroll
    for (int j = 0; j < 4; j++)
#pragma unroll
      for (int p = 0; p < 4; p++)
        C[(long)(brow + wm * 32 + i * 16 + lk * 4 + p) * N + (bcol + wn * 64 + j * 16 + lr)] =
            acc[i][j][p];
}

// ---------------- fused RMSNorm + RoPE -> bf16, one wave per (t, head) -------
__global__ void k_norm_rope(const float* __restrict__ qkv_lin,
                            unsigned short* __restrict__ qb, unsigned short* __restrict__ kb,
                            const float* __restrict__ cosT, const float* __restrict__ sinT,
                            const float* __restrict__ qw, const float* __restrict__ kw) {
  int gw = (blockIdx.x * blockDim.x + threadIdx.x) >> 6;
  int lane = threadIdx.x & 63;
  int t = gw / (NH + NKV);
  int hh = gw % (NH + NKV);
  if (t >= T_TOK) return;
  const float* base;
  unsigned short* ob;
  const float* w;
  if (hh < NH) {
    base = qkv_lin + (long)t * 3072 + hh * HD;
    ob   = qb + (long)t * (NH * HD) + hh * HD;
    w = qw;
  } else {
    int kh = hh - NH;
    base = qkv_lin + (long)t * 3072 + 2048 + kh * HD;
    ob   = kb + (long)t * (NKV * HD) + kh * HD;
    w = kw;
  }
  float v = base[lane];
  float ss = v * v;
#pragma unroll
  for (int off = 1; off < 64; off <<= 1) ss += __shfl_xor(ss, off);
  float xn = v * rsqrtf(ss * (1.0f / HD) + 1e-6f) * w[lane];
  float other = __shfl_xor(xn, 32);
  float c = cosT[t * HD + lane], s = sinT[t * HD + lane];
  ob[lane] = f2bf(xn * c + (lane < 32 ? -other : other) * s);
}

// -------- V transpose: qkv_lin cols 2560.. (f32) -> [512][1024] bf16 ---------
__global__ __launch_bounds__(256) void k_vt(const float* __restrict__ qkv_lin,
                                            unsigned short* __restrict__ out) {
  __shared__ float t[32][33];
  int tx = threadIdx.x & 31, ty = threadIdx.x >> 5;
  int r0 = blockIdx.y * 32;
  int c0 = blockIdx.x * 32;
#pragma unroll
  for (int r = 0; r < 4; r++)
    t[ty + r * 8][tx] = qkv_lin[(long)(r0 + ty + r * 8) * 3072 + 2560 + c0 + tx];
  __syncthreads();
#pragma unroll
  for (int r = 0; r < 4; r++)
    out[(long)(c0 + ty + r * 8) * 1024 + r0 + tx] = f2bf(t[tx][ty + r * 8]);
}

// ------------- flash attention, KV-split: block = (qt, head, split) ----------
// 4 waves, each 16 q rows (q = lane&15, swapped QK^T). Split sp processes KV
// tiles sp, sp+4, ... <= qt. Writes unnormalized partials (O bf16, m/l f32).
#define LOADK(K0, K1, tile) do {                                               \
    const unsigned short* kp_ = kb + (long)((tile) * 64 + lr) * 512 + kvh * 64 + lk * 8; \
    _Pragma("unroll") for (int f_ = 0; f_ < 4; f_++) {                         \
      K0[f_] = *reinterpret_cast<const bf16x8*>(kp_ + (long)f_ * 16 * 512);    \
      K1[f_] = *reinterpret_cast<const bf16x8*>(kp_ + (long)f_ * 16 * 512 + 32); \
    }                                                                          \
  } while (0)

#define BODY(KC0, KC1, KN0, KN1, tile) do {                                    \
    const int s0_ = (tile) * 64;                                               \
    const unsigned short* vp_ = vtb + (long)(kvh * 64 + lr) * 1024 + s0_ + lk * 8; \
    bf16x8 vfr[8];                                                             \
    _Pragma("unroll") for (int fd = 0; fd < 4; fd++) {                         \
      vfr[fd]     = *reinterpret_cast<const bf16x8*>(vp_ + (long)fd * 16 * 1024);      \
      vfr[4 + fd] = *reinterpret_cast<const bf16x8*>(vp_ + (long)fd * 16 * 1024 + 32); \
    }                                                                          \
    f32x4 sacc[4];                                                             \
    __builtin_amdgcn_s_setprio(1);                                             \
    _Pragma("unroll") for (int f = 0; f < 4; f++) {                            \
      sacc[f] = __builtin_amdgcn_mfma_f32_16x16x32_bf16(KC0[f], qa0, z4, 0, 0, 0);      \
      sacc[f] = __builtin_amdgcn_mfma_f32_16x16x32_bf16(KC1[f], qa1, sacc[f], 0, 0, 0); \
    }                                                                          \
    __builtin_amdgcn_s_setprio(0);                                             \
    if ((tile) + NSPLIT < ntiles) LOADK(KN0, KN1, (tile) + NSPLIT);            \
    const bool diag_ = ((tile) == qt);                                         \
    float sv[4][4];                                                            \
    float tmax_ = -3.0e38f;                                                    \
    _Pragma("unroll") for (int f = 0; f < 4; f++)                              \
      _Pragma("unroll") for (int p = 0; p < 4; p++) {                          \
        float s_ = sacc[f][p] * SC;                                            \
        if (diag_ && (f * 16 + lk * 4 + p) > qrel) s_ = -3.0e38f;              \
        sv[f][p] = s_;                                                         \
        tmax_ = fmaxf(tmax_, s_);                                              \
      }                                                                        \
    tmax_ = fmaxf(tmax_, __shfl_xor(tmax_, 16));                               \
    tmax_ = fmaxf(tmax_, __shfl_xor(tmax_, 32));                               \
    float mn_ = fmaxf(m2, tmax_);                                              \
    float r_ = exp2f(m2 - mn_);                                                \
    m2 = mn_;                                                                  \
    float rp_[4];                                                              \
    _Pragma("unroll") for (int p = 0; p < 4; p++)                              \
      rp_[p] = __shfl(r_, (lane & 48) | (lk * 4 + p));                         \
    float ps_ = 0.f;                                                           \
    _Pragma("unroll") for (int f = 0; f < 4; f++) {                            \
      float e0 = exp2f(sv[f][0] - mn_), e1 = exp2f(sv[f][1] - mn_);            \
      float e2 = exp2f(sv[f][2] - mn_), e3 = exp2f(sv[f][3] - mn_);            \
      ps_ += (e0 + e1) + (e2 + e3);                                            \
      uint2 pk_;                                                               \
      pk_.x = (unsigned)f2bf(e0) | ((unsigned)f2bf(e1) << 16);                 \
      pk_.y = (unsigned)f2bf(e2) | ((unsigned)f2bf(e3) << 16);                 \
      *reinterpret_cast<uint2*>(pbase + lr * 128 + ((f * 32 + lk * 8) ^ pswz)) = pk_; \
    }                                                                          \
    lp = lp * r_ + ps_;                                                        \
    _Pragma("unroll") for (int fd = 0; fd < 4; fd++)                           \
      _Pragma("unroll") for (int p = 0; p < 4; p++) o[fd][p] *= rp_[p];        \
    __builtin_amdgcn_s_setprio(1);                                             \
    _Pragma("unroll") for (int ks = 0; ks < 2; ks++) {                         \
      bf16x8 pa_ = *reinterpret_cast<const bf16x8*>(                           \
          pbase + lr * 128 + ((ks * 64 + lk * 16) ^ pswz));                    \
      _Pragma("unroll") for (int fd = 0; fd < 4; fd++)                         \
        o[fd] = __builtin_amdgcn_mfma_f32_16x16x32_bf16(pa_, vfr[ks * 4 + fd], o[fd], 0, 0, 0); \
    }                                                                          \
    __builtin_amdgcn_s_setprio(0);                                             \
  } while (0)

__global__ __launch_bounds__(256, 4) void k_flash(
    const unsigned short* __restrict__ qb, const unsigned short* __restrict__ kb,
    const unsigned short* __restrict__ vtb, unsigned short* __restrict__ Opart,
    float2* __restrict__ ml) {
  const int qt = blockIdx.x;
  const int h  = blockIdx.y;
  const int sp = blockIdx.z;
  if (sp > qt) return;
  __shared__ unsigned short plds[4 * 16 * 64];
  const int kvh = h >> 2;
  const int lane = threadIdx.x & 63;
  const int wave = threadIdx.x >> 6;
  const int lr = lane & 15, lk = lane >> 4;
  const int qrow = qt * 64 + wave * 16;
  const int qrel = wave * 16 + lr;
  const int pswz = (lr & 7) << 4;
  char* pbase = (char*)plds + wave * 2048;
  const float SC = 0.125f * 1.44269504f;
  const f32x4 z4 = {0.f, 0.f, 0.f, 0.f};

  const unsigned short* qp = qb + (long)(qrow + lr) * (NH * HD) + h * HD + lk * 8;
  bf16x8 qa0 = *reinterpret_cast<const bf16x8*>(qp);
  bf16x8 qa1 = *reinterpret_cast<const bf16x8*>(qp + 32);

  f32x4 o[4];
#pragma unroll
  for (int f = 0; f < 4; f++) o[f] = z4;
  float m2 = -3.0e38f;
  float lp = 0.f;

  const int ntiles = qt + 1;
  bf16x8 kA0[4], kA1[4], kB0[4], kB1[4];
  LOADK(kA0, kA1, sp);
  for (int t = sp; t < ntiles; t += 2 * NSPLIT) {
    BODY(kA0, kA1, kB0, kB1, t);
    if (t + NSPLIT >= ntiles) break;
    BODY(kB0, kB1, kA0, kA1, t + NSPLIT);
  }

  // lane-partial l -> full row sum (row = lr of this wave's strip)
  lp += __shfl_xor(lp, 16);
  lp += __shfl_xor(lp, 32);
  if (lk == 0) {
    float2 mlv; mlv.x = m2; mlv.y = lp;
    ml[((long)sp * NH + h) * T_TOK + qrow + lr] = mlv;
  }
  // raw (unnormalized) O partial, bf16
#pragma unroll
  for (int fd = 0; fd < 4; fd++)
#pragma unroll
    for (int p = 0; p < 4; p++) {
      long row = ((long)sp * NH + h) * T_TOK + qrow + lk * 4 + p;
      Opart[row * HD + fd * 16 + lr] = f2bf(o[fd][p]);
    }
}

// ------------- combine: merge <=4 KV-split partials per (h, t) row -----------
__global__ __launch_bounds__(256) void k_comb(
    const unsigned short* __restrict__ Opart, const float2* __restrict__ ml,
    unsigned short* __restrict__ ao) {
  int w = (blockIdx.x * blockDim.x + threadIdx.x) >> 6;  // (h,t) index
  int lane = threadIdx.x & 63;
  int h = w >> 10, t = w & 1023;
  int qt = t >> 6;
  int nv = min(qt + 1, NSPLIT);
  float mv[NSPLIT], lv[NSPLIT];
  float M = -3.0e38f;
#pragma unroll
  for (int i = 0; i < NSPLIT; i++) {
    if (i < nv) {
      float2 x = ml[((long)i * NH + h) * T_TOK + t];
      mv[i] = x.x; lv[i] = x.y;
    } else { mv[i] = -3.0e38f; lv[i] = 0.f; }
    M = fmaxf(M, mv[i]);
  }
  float L = 0.f, O = 0.f;
#pragma unroll
  for (int i = 0; i < NSPLIT; i++) {
    float wgt = exp2f(mv[i] - M);
    L += lv[i] * wgt;
    float ov = (i < nv) ? bf2f(Opart[(((long)i * NH + h) * T_TOK + t) * HD + lane]) : 0.f;
    O += ov * wgt;
  }
  ao[(long)t * (NH * HD) + h * HD + lane] = f2bf(O / L);
}

extern "C" void kernel_launch(void* const* d_in, const int* in_sizes, int n_in,
                              void* d_out, int out_size, void* d_ws, size_t ws_size,
                              hipStream_t stream) {
  const float* x    = (const float*)d_in[0];
  const float* cosT = (const float*)d_in[3];
  const float* sinT = (const float*)d_in[5];
  const float* Wq   = (const float*)d_in[7];
  const float* Wk   = (const float*)d_in[8];
  const float* Wv   = (const float*)d_in[9];
  const float* Wo   = (const float*)d_in[10];
  const float* qw   = (const float*)d_in[11];
  const float* kw   = (const float*)d_in[12];
  float* out = (float*)d_out;

  char* ws = (char*)d_ws;
  // phase-1 regions (dead before flash):
  unsigned short* xb    = (unsigned short*)(ws);               // 0..4 MB
  unsigned short* Wqkv  = (unsigned short*)(ws + (4u << 20));  // 4..16 MB
  float* qkv_lin = (float*)(ws + (24u << 20));                 // 24..36 MB
  // live-late regions:
  unsigned short* Wob   = (unsigned short*)(ws + (16u << 20)); // 16..24 MB
  unsigned short* qbb = (unsigned short*)(ws + (36u << 20));   // 36..40 MB
  unsigned short* kbb = (unsigned short*)(ws + (40u << 20));   // 40..41 MB
  unsigned short* vtb = (unsigned short*)(ws + (41u << 20));   // 41..42 MB
  unsigned short* ao  = (unsigned short*)(ws + (42u << 20));   // 42..46 MB
  // flash partials (reuse phase-1 regions):
  unsigned short* Opart = (unsigned short*)(ws);               // 0..16 MB (4 splits x 4 MB)
  float2* mlp           = (float2*)(ws + (24u << 20));         // 24..25 MB

  // all fp32 -> bf16 conversions in one launch
  k_cvt_all<<<12288, 256, 0, stream>>>(x, Wq, Wk, Wv, Wo, xb, Wqkv, Wob);

  // fused QKV projection: [1024][3072] = x * Wqkv^T
  k_gemm2<<<dim3(24, 16), 256, 0, stream>>>(xb, Wqkv, qkv_lin, 3072, 2048);

  // RMSNorm + RoPE -> bf16 q/k
  k_norm_rope<<<(T_TOK * (NH + NKV) * 64) / 256, 256, 0, stream>>>(
      qkv_lin, qbb, kbb, cosT, sinT, qw, kw);

  // V^T bf16 for PV B-operand
  k_vt<<<dim3(16, 32), 256, 0, stream>>>(qkv_lin, vtb);

  // flash attention, KV-split partials
  k_flash<<<dim3(16, 32, NSPLIT), 256, 0, stream>>>(qbb, kbb, vtb, Opart, mlp);

  // combine partials -> bf16 [T][H*HD]
  k_comb<<<NH * T_TOK / 4, 256, 0, stream>>>(Opart, mlp, ao);

  // output projection -> fp32 d_out
  k_gemm2<<<dim3(16, 16), 256, 0, stream>>>(ao, Wob, out, 2048, 2048);
}

// Round 6
// 267.407 us; speedup vs baseline: 1.0621x; 1.0621x over previous
//
#include <hip/hip_runtime.h>

typedef __bf16 bf16x8 __attribute__((ext_vector_type(8)));
typedef float f32x4 __attribute__((ext_vector_type(4)));

#define T_TOK 1024
#define DIN   2048
#define NH    32
#define NKV   8
#define HD    64

__device__ __forceinline__ unsigned short f2bf(float f) {
  unsigned int u = __float_as_uint(f);
  unsigned int r = (u + 0x7fffu + ((u >> 16) & 1u)) >> 16;
  return (unsigned short)r;
}

__device__ __forceinline__ void glds16(const void* g, void* lds) {
  __builtin_amdgcn_global_load_lds(
      (const __attribute__((address_space(1))) void*)g,
      (__attribute__((address_space(3))) void*)lds, 16, 0, 0);
}

// ------------- fused fp32 -> bf16 convert for all 5 operands, 1 launch -------
__global__ __launch_bounds__(256) void k_cvt_all(
    const float* __restrict__ x,  const float* __restrict__ wq,
    const float* __restrict__ wk, const float* __restrict__ wv,
    const float* __restrict__ wo, unsigned short* __restrict__ xb,
    unsigned short* __restrict__ wqkv, unsigned short* __restrict__ wob) {
  const long NX = 1l << 21, NWQ = 1l << 22, NWK = 1l << 20, NWV = 1l << 20;
  long i4 = ((long)blockIdx.x * blockDim.x + threadIdx.x) * 4;
  const float* src;
  unsigned short* dst;
  long off;
  if (i4 < NX)                       { src = x;  dst = xb;   off = i4; }
  else if (i4 < NX + NWQ)            { src = wq; dst = wqkv; off = i4 - NX; }
  else if (i4 < NX + NWQ + NWK)      { src = wk; dst = wqkv + NWQ; off = i4 - NX - NWQ; }
  else if (i4 < NX + NWQ + NWK + NWV){ src = wv; dst = wqkv + NWQ + NWK; off = i4 - NX - NWQ - NWK; }
  else                               { src = wo; dst = wob;  off = i4 - NX - NWQ - NWK - NWV; }
  float4 v = *reinterpret_cast<const float4*>(src + off);
  ushort4 o;
  o.x = f2bf(v.x); o.y = f2bf(v.y); o.z = f2bf(v.z); o.w = f2bf(v.w);
  *reinterpret_cast<ushort4*>(dst + off) = o;
}

// ------- bf16 MFMA GEMM, LDS-staged 2-phase: C[M][N] = A[M][K] * B[N][K]^T ---
// BM=64, BN template (64 or 128), BK=64, 4 waves (2x2), wave tile 32 x BN/2.
template<int BN>
__global__ __launch_bounds__(256) void k_gemm2(
    const unsigned short* __restrict__ A, const unsigned short* __restrict__ B,
    float* __restrict__ C, int N, int K) {
  constexpr int NJ = BN / 32;       // b-frags per wave
  constexpr int NBS = BN / 32;      // B staging iters (BN/8 strips / 4 waves)
  __shared__ unsigned short As[2][64 * 64];
  __shared__ unsigned short Bs[2][BN * 64];
  const int lane = threadIdx.x & 63;
  const int wave = threadIdx.x >> 6;
  const int wm = wave >> 1, wn = wave & 1;
  const int lr = lane & 15, lk = lane >> 4;
  const int brow = blockIdx.y * 64;
  const int bcol = blockIdx.x * BN;

  const int srow = lane >> 3;
  const int scol = ((lane & 7) ^ srow) * 8;
  const unsigned short* Ag = A + (long)(brow + srow) * K + scol;
  const unsigned short* Bg = B + (long)(bcol + srow) * K + scol;

  f32x4 acc[2][NJ];
#pragma unroll
  for (int i = 0; i < 2; i++)
#pragma unroll
    for (int j = 0; j < NJ; j++) acc[i][j] = (f32x4){0.f, 0.f, 0.f, 0.f};

  const int swz = (lr & 7) << 4;
  const int nt = K / 64;
  int cur = 0;

#pragma unroll
  for (int i = 0; i < 2; i++) {
    int strip = i * 4 + wave;
    glds16(Ag + (long)strip * 8 * K, (char*)As[0] + strip * 1024);
  }
#pragma unroll
  for (int i = 0; i < NBS; i++) {
    int strip = i * 4 + wave;
    glds16(Bg + (long)strip * 8 * K, (char*)Bs[0] + strip * 1024);
  }
  __syncthreads();

  for (int t = 0; t < nt; t++) {
    if (t + 1 < nt) {
      const int kk = (t + 1) * 64;
#pragma unroll
      for (int i = 0; i < 2; i++) {
        int strip = i * 4 + wave;
        glds16(Ag + (long)strip * 8 * K + kk, (char*)As[cur ^ 1] + strip * 1024);
      }
#pragma unroll
      for (int i = 0; i < NBS; i++) {
        int strip = i * 4 + wave;
        glds16(Bg + (long)strip * 8 * K + kk, (char*)Bs[cur ^ 1] + strip * 1024);
      }
    }
#pragma unroll
    for (int s = 0; s < 2; s++) {
      bf16x8 a[2], b[NJ];
#pragma unroll
      for (int i = 0; i < 2; i++) {
        int row = wm * 32 + i * 16 + lr;
        a[i] = *reinterpret_cast<const bf16x8*>(
            (const char*)As[cur] + row * 128 + ((s * 64 + lk * 16) ^ swz));
      }
#pragma unroll
      for (int j = 0; j < NJ; j++) {
        int row = wn * (BN / 2) + j * 16 + lr;
        b[j] = *reinterpret_cast<const bf16x8*>(
            (const char*)Bs[cur] + row * 128 + ((s * 64 + lk * 16) ^ swz));
      }
#pragma unroll
      for (int i = 0; i < 2; i++)
#pragma unroll
        for (int j = 0; j < NJ; j++)
          acc[i][j] = __builtin_amdgcn_mfma_f32_16x16x32_bf16(a[i], b[j], acc[i][j], 0, 0, 0);
    }
    __syncthreads();
    cur ^= 1;
  }

#pragma unroll
  for (int i = 0; i < 2; i++)
#pragma unroll
    for (int j = 0; j < NJ; j++)
#pragma unroll
      for (int p = 0; p < 4; p++)
        C[(long)(brow + wm * 32 + i * 16 + lk * 4 + p) * N +
          (bcol + wn * (BN / 2) + j * 16 + lr)] = acc[i][j][p];
}

// ---------------- fused RMSNorm + RoPE -> bf16, one wave per (t, head) -------
__global__ void k_norm_rope(const float* __restrict__ qkv_lin,
                            unsigned short* __restrict__ qb, unsigned short* __restrict__ kb,
                            const float* __restrict__ cosT, const float* __restrict__ sinT,
                            const float* __restrict__ qw, const float* __restrict__ kw) {
  int gw = (blockIdx.x * blockDim.x + threadIdx.x) >> 6;
  int lane = threadIdx.x & 63;
  int t = gw / (NH + NKV);
  int hh = gw % (NH + NKV);
  if (t >= T_TOK) return;
  const float* base;
  unsigned short* ob;
  const float* w;
  if (hh < NH) {
    base = qkv_lin + (long)t * 3072 + hh * HD;
    ob   = qb + (long)t * (NH * HD) + hh * HD;
    w = qw;
  } else {
    int kh = hh - NH;
    base = qkv_lin + (long)t * 3072 + 2048 + kh * HD;
    ob   = kb + (long)t * (NKV * HD) + kh * HD;
    w = kw;
  }
  float v = base[lane];
  float ss = v * v;
#pragma unroll
  for (int off = 1; off < 64; off <<= 1) ss += __shfl_xor(ss, off);
  float xn = v * rsqrtf(ss * (1.0f / HD) + 1e-6f) * w[lane];
  float other = __shfl_xor(xn, 32);
  float c = cosT[t * HD + lane], s = sinT[t * HD + lane];
  ob[lane] = f2bf(xn * c + (lane < 32 ? -other : other) * s);
}

// -------- V transpose: qkv_lin cols 2560.. (f32) -> [512][1024] bf16 ---------
__global__ __launch_bounds__(256) void k_vt(const float* __restrict__ qkv_lin,
                                            unsigned short* __restrict__ out) {
  __shared__ float t[32][33];
  int tx = threadIdx.x & 31, ty = threadIdx.x >> 5;
  int r0 = blockIdx.y * 32;
  int c0 = blockIdx.x * 32;
#pragma unroll
  for (int r = 0; r < 4; r++)
    t[ty + r * 8][tx] = qkv_lin[(long)(r0 + ty + r * 8) * 3072 + 2560 + c0 + tx];
  __syncthreads();
#pragma unroll
  for (int r = 0; r < 4; r++)
    out[(long)(c0 + ty + r * 8) * 1024 + r0 + tx] = f2bf(t[tx][ty + r * 8]);
}

// -------- flash attention: 1-wave blocks, 16 q rows each (swapped QK^T) ------
#define LOADK(K0, K1, tile) do {                                               \
    const unsigned short* kp_ = kb + (long)((tile) * 64 + lr) * 512 + kvh * 64 + lk * 8; \
    _Pragma("unroll") for (int f_ = 0; f_ < 4; f_++) {                         \
      K0[f_] = *reinterpret_cast<const bf16x8*>(kp_ + (long)f_ * 16 * 512);    \
      K1[f_] = *reinterpret_cast<const bf16x8*>(kp_ + (long)f_ * 16 * 512 + 32); \
    }                                                                          \
  } while (0)

#define BODY(KC0, KC1, KN0, KN1, tile) do {                                    \
    const int s0_ = (tile) * 64;                                               \
    const unsigned short* vp_ = vtb + (long)(kvh * 64 + lr) * 1024 + s0_ + lk * 8; \
    bf16x8 vfr[8];                                                             \
    _Pragma("unroll") for (int fd = 0; fd < 4; fd++) {                         \
      vfr[fd]     = *reinterpret_cast<const bf16x8*>(vp_ + (long)fd * 16 * 1024);      \
      vfr[4 + fd] = *reinterpret_cast<const bf16x8*>(vp_ + (long)fd * 16 * 1024 + 32); \
    }                                                                          \
    f32x4 sacc[4];                                                             \
    __builtin_amdgcn_s_setprio(1);                                             \
    _Pragma("unroll") for (int f = 0; f < 4; f++) {                            \
      sacc[f] = __builtin_amdgcn_mfma_f32_16x16x32_bf16(KC0[f], qa0, z4, 0, 0, 0);      \
      sacc[f] = __builtin_amdgcn_mfma_f32_16x16x32_bf16(KC1[f], qa1, sacc[f], 0, 0, 0); \
    }                                                                          \
    __builtin_amdgcn_s_setprio(0);                                             \
    if ((tile) + 1 < ntiles) LOADK(KN0, KN1, (tile) + 1);                      \
    const bool diag_ = ((tile) == qt);                                         \
    float sv[4][4];                                                            \
    float tmax_ = -3.0e38f;                                                    \
    _Pragma("unroll") for (int f = 0; f < 4; f++)                              \
      _Pragma("unroll") for (int p = 0; p < 4; p++) {                          \
        float s_ = sacc[f][p] * SC;                                            \
        if (diag_ && (f * 16 + lk * 4 + p) > qrel) s_ = -3.0e38f;              \
        sv[f][p] = s_;                                                         \
        tmax_ = fmaxf(tmax_, s_);                                              \
      }                                                                        \
    tmax_ = fmaxf(tmax_, __shfl_xor(tmax_, 16));                               \
    tmax_ = fmaxf(tmax_, __shfl_xor(tmax_, 32));                               \
    float mn_ = fmaxf(m2, tmax_);                                              \
    float r_ = exp2f(m2 - mn_);                                                \
    m2 = mn_;                                                                  \
    float rp_[4];                                                              \
    _Pragma("unroll") for (int p = 0; p < 4; p++)                              \
      rp_[p] = __shfl(r_, (lane & 48) | (lk * 4 + p));                         \
    float ps_ = 0.f;                                                           \
    _Pragma("unroll") for (int f = 0; f < 4; f++) {                            \
      float e0 = exp2f(sv[f][0] - mn_), e1 = exp2f(sv[f][1] - mn_);            \
      float e2 = exp2f(sv[f][2] - mn_), e3 = exp2f(sv[f][3] - mn_);            \
      ps_ += (e0 + e1) + (e2 + e3);                                            \
      uint2 pk_;                                                               \
      pk_.x = (unsigned)f2bf(e0) | ((unsigned)f2bf(e1) << 16);                 \
      pk_.y = (unsigned)f2bf(e2) | ((unsigned)f2bf(e3) << 16);                 \
      *reinterpret_cast<uint2*>(pbase + lr * 128 + ((f * 32 + lk * 8) ^ pswz)) = pk_; \
    }                                                                          \
    lp = lp * r_ + ps_;                                                        \
    _Pragma("unroll") for (int fd = 0; fd < 4; fd++)                           \
      _Pragma("unroll") for (int p = 0; p < 4; p++) o[fd][p] *= rp_[p];        \
    __builtin_amdgcn_s_setprio(1);                                             \
    _Pragma("unroll") for (int ks = 0; ks < 2; ks++) {                         \
      bf16x8 pa_ = *reinterpret_cast<const bf16x8*>(                           \
          pbase + lr * 128 + ((ks * 64 + lk * 16) ^ pswz));                    \
      _Pragma("unroll") for (int fd = 0; fd < 4; fd++)                         \
        o[fd] = __builtin_amdgcn_mfma_f32_16x16x32_bf16(pa_, vfr[ks * 4 + fd], o[fd], 0, 0, 0); \
    }                                                                          \
    __builtin_amdgcn_s_setprio(0);                                             \
  } while (0)

__global__ __launch_bounds__(64, 4) void k_flash(
    const unsigned short* __restrict__ qb, const unsigned short* __restrict__ kb,
    const unsigned short* __restrict__ vtb, unsigned short* __restrict__ ao) {
  __shared__ unsigned short plds[16 * 64];  // one-wave 16x64 bf16 P strip
  const int rb = 63 - blockIdx.x;   // 16-row q block, longest-first
  const int h  = blockIdx.y;
  const int kvh = h >> 2;
  const int lane = threadIdx.x & 63;
  const int lr = lane & 15, lk = lane >> 4;
  const int qrow = rb * 16;
  const int qt = rb >> 2;               // diag 64-key tile
  const int qrel = (rb & 3) * 16 + lr;  // row within covering 64-tile
  const int pswz = (lr & 7) << 4;
  char* pbase = (char*)plds;
  const float SC = 0.125f * 1.44269504f;  // 1/sqrt(64) * log2(e)
  const f32x4 z4 = {0.f, 0.f, 0.f, 0.f};

  const unsigned short* qp = qb + (long)(qrow + lr) * (NH * HD) + h * HD + lk * 8;
  bf16x8 qa0 = *reinterpret_cast<const bf16x8*>(qp);
  bf16x8 qa1 = *reinterpret_cast<const bf16x8*>(qp + 32);

  f32x4 o[4];
#pragma unroll
  for (int f = 0; f < 4; f++) o[f] = z4;
  float m2 = -3.0e38f;  // running max (exp2 domain), lane q-row = lr
  float lp = 0.f;       // lane-partial denominator

  const int ntiles = qt + 1;
  bf16x8 kA0[4], kA1[4], kB0[4], kB1[4];
  LOADK(kA0, kA1, 0);
  for (int t = 0; t < ntiles; t += 2) {
    BODY(kA0, kA1, kB0, kB1, t);
    if (t + 1 >= ntiles) break;
    BODY(kB0, kB1, kA0, kA1, t + 1);
  }

  lp += __shfl_xor(lp, 16);
  lp += __shfl_xor(lp, 32);
  float lo[4];
#pragma unroll
  for (int p = 0; p < 4; p++) lo[p] = __shfl(lp, (lane & 48) | (lk * 4 + p));
#pragma unroll
  for (int fd = 0; fd < 4; fd++)
#pragma unroll
    for (int p = 0; p < 4; p++) {
      int qg = qrow + lk * 4 + p;
      int d = fd * 16 + lr;
      ao[(long)qg * (NH * HD) + h * HD + d] = f2bf(o[fd][p] / lo[p]);
    }
}

extern "C" void kernel_launch(void* const* d_in, const int* in_sizes, int n_in,
                              void* d_out, int out_size, void* d_ws, size_t ws_size,
                              hipStream_t stream) {
  const float* x    = (const float*)d_in[0];
  const float* cosT = (const float*)d_in[3];
  const float* sinT = (const float*)d_in[5];
  const float* Wq   = (const float*)d_in[7];
  const float* Wk   = (const float*)d_in[8];
  const float* Wv   = (const float*)d_in[9];
  const float* Wo   = (const float*)d_in[10];
  const float* qw   = (const float*)d_in[11];
  const float* kw   = (const float*)d_in[12];
  float* out = (float*)d_out;

  char* ws = (char*)d_ws;
  unsigned short* xb    = (unsigned short*)(ws);               // 0..4 MB
  unsigned short* Wqkv  = (unsigned short*)(ws + (4u << 20));  // 4..16 MB
  unsigned short* Wob   = (unsigned short*)(ws + (16u << 20)); // 16..24 MB
  float* qkv_lin = (float*)(ws + (24u << 20));                 // 24..36 MB
  unsigned short* qbb = (unsigned short*)(ws + (36u << 20));   // 36..40 MB
  unsigned short* kbb = (unsigned short*)(ws + (40u << 20));   // 40..41 MB
  unsigned short* vtb = (unsigned short*)(ws + (41u << 20));   // 41..42 MB
  unsigned short* ao  = (unsigned short*)(ws + (42u << 20));   // 42..46 MB

  // all fp32 -> bf16 conversions in one launch
  k_cvt_all<<<12288, 256, 0, stream>>>(x, Wq, Wk, Wv, Wo, xb, Wqkv, Wob);

  // fused QKV projection: [1024][3072] = x * Wqkv^T  (768 blocks, 3/CU)
  k_gemm2<64><<<dim3(48, 16), 256, 0, stream>>>(xb, Wqkv, qkv_lin, 3072, 2048);

  // RMSNorm + RoPE -> bf16 q/k
  k_norm_rope<<<(T_TOK * (NH + NKV) * 64) / 256, 256, 0, stream>>>(
      qkv_lin, qbb, kbb, cosT, sinT, qw, kw);

  // V^T bf16 for PV B-operand
  k_vt<<<dim3(16, 32), 256, 0, stream>>>(qkv_lin, vtb);

  // flash attention -> bf16 [T][H*HD]  (2048 one-wave blocks)
  k_flash<<<dim3(64, 32), 64, 0, stream>>>(qbb, kbb, vtb, ao);

  // output projection -> fp32 d_out  (512 blocks, 2/CU)
  k_gemm2<64><<<dim3(32, 16), 256, 0, stream>>>(ao, Wob, out, 2048, 2048);
}

// Round 7
// 230.284 us; speedup vs baseline: 1.2333x; 1.1612x over previous
//
#include <hip/hip_runtime.h>

typedef __bf16 bf16x8 __attribute__((ext_vector_type(8)));
typedef float f32x4 __attribute__((ext_vector_type(4)));

#define T_TOK 1024
#define DIN   2048
#define NH    32
#define NKV   8
#define HD    64

__device__ __forceinline__ unsigned short f2bf(float f) {
  unsigned int u = __float_as_uint(f);
  unsigned int r = (u + 0x7fffu + ((u >> 16) & 1u)) >> 16;
  return (unsigned short)r;
}

__device__ __forceinline__ void glds16(const void* g, void* lds) {
  __builtin_amdgcn_global_load_lds(
      (const __attribute__((address_space(1))) void*)g,
      (__attribute__((address_space(3))) void*)lds, 16, 0, 0);
}

// ------------- fused fp32 -> bf16 convert for all 5 operands, 1 launch -------
__global__ __launch_bounds__(256) void k_cvt_all(
    const float* __restrict__ x,  const float* __restrict__ wq,
    const float* __restrict__ wk, const float* __restrict__ wv,
    const float* __restrict__ wo, unsigned short* __restrict__ xb,
    unsigned short* __restrict__ wqkv, unsigned short* __restrict__ wob) {
  const long NX = 1l << 21, NWQ = 1l << 22, NWK = 1l << 20, NWV = 1l << 20;
  long i4 = ((long)blockIdx.x * blockDim.x + threadIdx.x) * 4;
  const float* src;
  unsigned short* dst;
  long off;
  if (i4 < NX)                       { src = x;  dst = xb;   off = i4; }
  else if (i4 < NX + NWQ)            { src = wq; dst = wqkv; off = i4 - NX; }
  else if (i4 < NX + NWQ + NWK)      { src = wk; dst = wqkv + NWQ; off = i4 - NX - NWQ; }
  else if (i4 < NX + NWQ + NWK + NWV){ src = wv; dst = wqkv + NWQ + NWK; off = i4 - NX - NWQ - NWK; }
  else                               { src = wo; dst = wob;  off = i4 - NX - NWQ - NWK - NWV; }
  float4 v = *reinterpret_cast<const float4*>(src + off);
  ushort4 o;
  o.x = f2bf(v.x); o.y = f2bf(v.y); o.z = f2bf(v.z); o.w = f2bf(v.w);
  *reinterpret_cast<ushort4*>(dst + off) = o;
}

// ------- bf16 MFMA GEMM, LDS-staged 2-phase: C[M][N] = A[M][K] * B[N][K]^T ---
// BM=64, BN template, BK=64, 4 waves (2x2), wave tile 32 x BN/2.
template<int BN>
__global__ __launch_bounds__(256) void k_gemm2(
    const unsigned short* __restrict__ A, const unsigned short* __restrict__ B,
    float* __restrict__ C, int N, int K) {
  constexpr int NJ = BN / 32;
  constexpr int NBS = BN / 32;
  __shared__ unsigned short As[2][64 * 64];
  __shared__ unsigned short Bs[2][BN * 64];
  const int lane = threadIdx.x & 63;
  const int wave = threadIdx.x >> 6;
  const int wm = wave >> 1, wn = wave & 1;
  const int lr = lane & 15, lk = lane >> 4;
  const int brow = blockIdx.y * 64;
  const int bcol = blockIdx.x * BN;

  const int srow = lane >> 3;
  const int scol = ((lane & 7) ^ srow) * 8;
  const unsigned short* Ag = A + (long)(brow + srow) * K + scol;
  const unsigned short* Bg = B + (long)(bcol + srow) * K + scol;

  f32x4 acc[2][NJ];
#pragma unroll
  for (int i = 0; i < 2; i++)
#pragma unroll
    for (int j = 0; j < NJ; j++) acc[i][j] = (f32x4){0.f, 0.f, 0.f, 0.f};

  const int swz = (lr & 7) << 4;
  const int nt = K / 64;
  int cur = 0;

#pragma unroll
  for (int i = 0; i < 2; i++) {
    int strip = i * 4 + wave;
    glds16(Ag + (long)strip * 8 * K, (char*)As[0] + strip * 1024);
  }
#pragma unroll
  for (int i = 0; i < NBS; i++) {
    int strip = i * 4 + wave;
    glds16(Bg + (long)strip * 8 * K, (char*)Bs[0] + strip * 1024);
  }
  __syncthreads();

  for (int t = 0; t < nt; t++) {
    if (t + 1 < nt) {
      const int kk = (t + 1) * 64;
#pragma unroll
      for (int i = 0; i < 2; i++) {
        int strip = i * 4 + wave;
        glds16(Ag + (long)strip * 8 * K + kk, (char*)As[cur ^ 1] + strip * 1024);
      }
#pragma unroll
      for (int i = 0; i < NBS; i++) {
        int strip = i * 4 + wave;
        glds16(Bg + (long)strip * 8 * K + kk, (char*)Bs[cur ^ 1] + strip * 1024);
      }
    }
#pragma unroll
    for (int s = 0; s < 2; s++) {
      bf16x8 a[2], b[NJ];
#pragma unroll
      for (int i = 0; i < 2; i++) {
        int row = wm * 32 + i * 16 + lr;
        a[i] = *reinterpret_cast<const bf16x8*>(
            (const char*)As[cur] + row * 128 + ((s * 64 + lk * 16) ^ swz));
      }
#pragma unroll
      for (int j = 0; j < NJ; j++) {
        int row = wn * (BN / 2) + j * 16 + lr;
        b[j] = *reinterpret_cast<const bf16x8*>(
            (const char*)Bs[cur] + row * 128 + ((s * 64 + lk * 16) ^ swz));
      }
#pragma unroll
      for (int i = 0; i < 2; i++)
#pragma unroll
        for (int j = 0; j < NJ; j++)
          acc[i][j] = __builtin_amdgcn_mfma_f32_16x16x32_bf16(a[i], b[j], acc[i][j], 0, 0, 0);
    }
    __syncthreads();
    cur ^= 1;
  }

#pragma unroll
  for (int i = 0; i < 2; i++)
#pragma unroll
    for (int j = 0; j < NJ; j++)
#pragma unroll
      for (int p = 0; p < 4; p++)
        C[(long)(brow + wm * 32 + i * 16 + lk * 4 + p) * N +
          (bcol + wn * (BN / 2) + j * 16 + lr)] = acc[i][j][p];
}

// ---------------- fused RMSNorm + RoPE -> bf16, one wave per (t, head) -------
__global__ void k_norm_rope(const float* __restrict__ qkv_lin,
                            unsigned short* __restrict__ qb, unsigned short* __restrict__ kb,
                            const float* __restrict__ cosT, const float* __restrict__ sinT,
                            const float* __restrict__ qw, const float* __restrict__ kw) {
  int gw = (blockIdx.x * blockDim.x + threadIdx.x) >> 6;
  int lane = threadIdx.x & 63;
  int t = gw / (NH + NKV);
  int hh = gw % (NH + NKV);
  if (t >= T_TOK) return;
  const float* base;
  unsigned short* ob;
  const float* w;
  if (hh < NH) {
    base = qkv_lin + (long)t * 3072 + hh * HD;
    ob   = qb + (long)t * (NH * HD) + hh * HD;
    w = qw;
  } else {
    int kh = hh - NH;
    base = qkv_lin + (long)t * 3072 + 2048 + kh * HD;
    ob   = kb + (long)t * (NKV * HD) + kh * HD;
    w = kw;
  }
  float v = base[lane];
  float ss = v * v;
#pragma unroll
  for (int off = 1; off < 64; off <<= 1) ss += __shfl_xor(ss, off);
  float xn = v * rsqrtf(ss * (1.0f / HD) + 1e-6f) * w[lane];
  float other = __shfl_xor(xn, 32);
  float c = cosT[t * HD + lane], s = sinT[t * HD + lane];
  ob[lane] = f2bf(xn * c + (lane < 32 ? -other : other) * s);
}

// -------- V transpose: qkv_lin cols 2560.. (f32) -> [512][1024] bf16 ---------
__global__ __launch_bounds__(256) void k_vt(const float* __restrict__ qkv_lin,
                                            unsigned short* __restrict__ out) {
  __shared__ float t[32][33];
  int tx = threadIdx.x & 31, ty = threadIdx.x >> 5;
  int r0 = blockIdx.y * 32;
  int c0 = blockIdx.x * 32;
#pragma unroll
  for (int r = 0; r < 4; r++)
    t[ty + r * 8][tx] = qkv_lin[(long)(r0 + ty + r * 8) * 3072 + 2560 + c0 + tx];
  __syncthreads();
#pragma unroll
  for (int r = 0; r < 4; r++)
    out[(long)(c0 + ty + r * 8) * 1024 + r0 + tx] = f2bf(t[tx][ty + r * 8]);
}

// -------- flash attention: 1-wave blocks, 16 q rows each (swapped QK^T) ------
// No software K-prefetch: with 2048 blocks, cross-wave TLP hides latency.
// K loads issue first, V loads second (stay outstanding under QK+softmax).
__global__ __launch_bounds__(64) void k_flash(
    const unsigned short* __restrict__ qb, const unsigned short* __restrict__ kb,
    const unsigned short* __restrict__ vtb, unsigned short* __restrict__ ao) {
  __shared__ unsigned short plds[16 * 64];  // one-wave 16x64 bf16 P strip
  const int rb = 63 - blockIdx.x;   // 16-row q block, longest-first
  const int h  = blockIdx.y;
  const int kvh = h >> 2;
  const int lane = threadIdx.x & 63;
  const int lr = lane & 15, lk = lane >> 4;
  const int qrow = rb * 16;
  const int qt = rb >> 2;               // diag 64-key tile
  const int qrel = (rb & 3) * 16 + lr;  // row within covering 64-tile
  const int pswz = (lr & 7) << 4;
  char* pbase = (char*)plds;
  const float SC = 0.125f * 1.44269504f;  // 1/sqrt(64) * log2(e)
  const f32x4 z4 = {0.f, 0.f, 0.f, 0.f};

  const unsigned short* qp = qb + (long)(qrow + lr) * (NH * HD) + h * HD + lk * 8;
  bf16x8 qa0 = *reinterpret_cast<const bf16x8*>(qp);
  bf16x8 qa1 = *reinterpret_cast<const bf16x8*>(qp + 32);

  f32x4 o[4];
#pragma unroll
  for (int f = 0; f < 4; f++) o[f] = z4;
  float m2 = -3.0e38f;  // running max (exp2 domain), lane q-row = lr
  float lp = 0.f;       // lane-partial denominator

  const int ntiles = qt + 1;
  for (int t = 0; t < ntiles; t++) {
    // K fragments (8x b128) — issued first
    const unsigned short* kp = kb + (long)(t * 64 + lr) * 512 + kvh * 64 + lk * 8;
    bf16x8 kf0[4], kf1[4];
#pragma unroll
    for (int f = 0; f < 4; f++) {
      kf0[f] = *reinterpret_cast<const bf16x8*>(kp + (long)f * 16 * 512);
      kf1[f] = *reinterpret_cast<const bf16x8*>(kp + (long)f * 16 * 512 + 32);
    }
    // V fragments (8x b128) — outstanding through QK + softmax
    const unsigned short* vp = vtb + (long)(kvh * 64 + lr) * 1024 + t * 64 + lk * 8;
    bf16x8 vfr[8];
#pragma unroll
    for (int fd = 0; fd < 4; fd++) {
      vfr[fd]     = *reinterpret_cast<const bf16x8*>(vp + (long)fd * 16 * 1024);
      vfr[4 + fd] = *reinterpret_cast<const bf16x8*>(vp + (long)fd * 16 * 1024 + 32);
    }
    // S^T strip: 64 keys x 16 q
    f32x4 sacc[4];
    __builtin_amdgcn_s_setprio(1);
#pragma unroll
    for (int f = 0; f < 4; f++) {
      sacc[f] = __builtin_amdgcn_mfma_f32_16x16x32_bf16(kf0[f], qa0, z4, 0, 0, 0);
      sacc[f] = __builtin_amdgcn_mfma_f32_16x16x32_bf16(kf1[f], qa1, sacc[f], 0, 0, 0);
    }
    __builtin_amdgcn_s_setprio(0);
    const bool diag = (t == qt);
    // scale + causal mask in place; running max over lane's 16 scores
    float tmax = -3.0e38f;
#pragma unroll
    for (int f = 0; f < 4; f++)
#pragma unroll
      for (int p = 0; p < 4; p++) {
        float s_ = sacc[f][p] * SC;
        if (diag && (f * 16 + lk * 4 + p) > qrel) s_ = -3.0e38f;
        sacc[f][p] = s_;
        tmax = fmaxf(tmax, s_);
      }
    tmax = fmaxf(tmax, __shfl_xor(tmax, 16));
    tmax = fmaxf(tmax, __shfl_xor(tmax, 32));
    float mn = fmaxf(m2, tmax);
    float r = exp2f(m2 - mn);
    m2 = mn;
    float rp[4];
#pragma unroll
    for (int p = 0; p < 4; p++)
      rp[p] = __shfl(r, (lane & 48) | (lk * 4 + p));
    float ps = 0.f;
#pragma unroll
    for (int f = 0; f < 4; f++) {
      float e0 = exp2f(sacc[f][0] - mn), e1 = exp2f(sacc[f][1] - mn);
      float e2 = exp2f(sacc[f][2] - mn), e3 = exp2f(sacc[f][3] - mn);
      ps += (e0 + e1) + (e2 + e3);
      uint2 pk;
      pk.x = (unsigned)f2bf(e0) | ((unsigned)f2bf(e1) << 16);
      pk.y = (unsigned)f2bf(e2) | ((unsigned)f2bf(e3) << 16);
      *reinterpret_cast<uint2*>(pbase + lr * 128 + ((f * 32 + lk * 8) ^ pswz)) = pk;
    }
    lp = lp * r + ps;
#pragma unroll
    for (int fd = 0; fd < 4; fd++)
#pragma unroll
      for (int p = 0; p < 4; p++) o[fd][p] *= rp[p];
    __builtin_amdgcn_s_setprio(1);
#pragma unroll
    for (int ks = 0; ks < 2; ks++) {
      bf16x8 pa = *reinterpret_cast<const bf16x8*>(
          pbase + lr * 128 + ((ks * 64 + lk * 16) ^ pswz));
#pragma unroll
      for (int fd = 0; fd < 4; fd++)
        o[fd] = __builtin_amdgcn_mfma_f32_16x16x32_bf16(pa, vfr[ks * 4 + fd], o[fd], 0, 0, 0);
    }
    __builtin_amdgcn_s_setprio(0);
  }

  lp += __shfl_xor(lp, 16);
  lp += __shfl_xor(lp, 32);
  float lo[4];
#pragma unroll
  for (int p = 0; p < 4; p++) lo[p] = __shfl(lp, (lane & 48) | (lk * 4 + p));
#pragma unroll
  for (int fd = 0; fd < 4; fd++)
#pragma unroll
    for (int p = 0; p < 4; p++) {
      int qg = qrow + lk * 4 + p;
      int d = fd * 16 + lr;
      ao[(long)qg * (NH * HD) + h * HD + d] = f2bf(o[fd][p] / lo[p]);
    }
}

extern "C" void kernel_launch(void* const* d_in, const int* in_sizes, int n_in,
                              void* d_out, int out_size, void* d_ws, size_t ws_size,
                              hipStream_t stream) {
  const float* x    = (const float*)d_in[0];
  const float* cosT = (const float*)d_in[3];
  const float* sinT = (const float*)d_in[5];
  const float* Wq   = (const float*)d_in[7];
  const float* Wk   = (const float*)d_in[8];
  const float* Wv   = (const float*)d_in[9];
  const float* Wo   = (const float*)d_in[10];
  const float* qw   = (const float*)d_in[11];
  const float* kw   = (const float*)d_in[12];
  float* out = (float*)d_out;

  char* ws = (char*)d_ws;
  unsigned short* xb    = (unsigned short*)(ws);               // 0..4 MB
  unsigned short* Wqkv  = (unsigned short*)(ws + (4u << 20));  // 4..16 MB
  unsigned short* Wob   = (unsigned short*)(ws + (16u << 20)); // 16..24 MB
  float* qkv_lin = (float*)(ws + (24u << 20));                 // 24..36 MB
  unsigned short* qbb = (unsigned short*)(ws + (36u << 20));   // 36..40 MB
  unsigned short* kbb = (unsigned short*)(ws + (40u << 20));   // 40..41 MB
  unsigned short* vtb = (unsigned short*)(ws + (41u << 20));   // 41..42 MB
  unsigned short* ao  = (unsigned short*)(ws + (42u << 20));   // 42..46 MB

  // all fp32 -> bf16 conversions in one launch
  k_cvt_all<<<12288, 256, 0, stream>>>(x, Wq, Wk, Wv, Wo, xb, Wqkv, Wob);

  // fused QKV projection: [1024][3072] = x * Wqkv^T  (768 blocks, 3/CU)
  k_gemm2<64><<<dim3(48, 16), 256, 0, stream>>>(xb, Wqkv, qkv_lin, 3072, 2048);

  // RMSNorm + RoPE -> bf16 q/k
  k_norm_rope<<<(T_TOK * (NH + NKV) * 64) / 256, 256, 0, stream>>>(
      qkv_lin, qbb, kbb, cosT, sinT, qw, kw);

  // V^T bf16 for PV B-operand
  k_vt<<<dim3(16, 32), 256, 0, stream>>>(qkv_lin, vtb);

  // flash attention -> bf16 [T][H*HD]  (2048 one-wave blocks)
  k_flash<<<dim3(64, 32), 64, 0, stream>>>(qbb, kbb, vtb, ao);

  // output projection -> fp32 d_out  (512 blocks, 2/CU)
  k_gemm2<64><<<dim3(32, 16), 256, 0, stream>>>(ao, Wob, out, 2048, 2048);
}

// Round 9
// 220.655 us; speedup vs baseline: 1.2871x; 1.0436x over previous
//
#include <hip/hip_runtime.h>

typedef __bf16 bf16x8 __attribute__((ext_vector_type(8)));
typedef float f32x4 __attribute__((ext_vector_type(4)));

#define T_TOK 1024
#define DIN   2048
#define NH    32
#define NKV   8
#define HD    64

__device__ __forceinline__ unsigned short f2bf(float f) {
  unsigned int u = __float_as_uint(f);
  unsigned int r = (u + 0x7fffu + ((u >> 16) & 1u)) >> 16;
  return (unsigned short)r;
}

__device__ __forceinline__ void glds16(const void* g, void* lds) {
  __builtin_amdgcn_global_load_lds(
      (const __attribute__((address_space(1))) void*)g,
      (__attribute__((address_space(3))) void*)lds, 16, 0, 0);
}

// ------------- fused fp32 -> bf16 convert for all 5 operands, 1 launch -------
__global__ __launch_bounds__(256) void k_cvt_all(
    const float* __restrict__ x,  const float* __restrict__ wq,
    const float* __restrict__ wk, const float* __restrict__ wv,
    const float* __restrict__ wo, unsigned short* __restrict__ xb,
    unsigned short* __restrict__ wqkv, unsigned short* __restrict__ wob) {
  const long NX = 1l << 21, NWQ = 1l << 22, NWK = 1l << 20, NWV = 1l << 20;
  long i4 = ((long)blockIdx.x * blockDim.x + threadIdx.x) * 4;
  const float* src;
  unsigned short* dst;
  long off;
  if (i4 < NX)                       { src = x;  dst = xb;   off = i4; }
  else if (i4 < NX + NWQ)            { src = wq; dst = wqkv; off = i4 - NX; }
  else if (i4 < NX + NWQ + NWK)      { src = wk; dst = wqkv + NWQ; off = i4 - NX - NWQ; }
  else if (i4 < NX + NWQ + NWK + NWV){ src = wv; dst = wqkv + NWQ + NWK; off = i4 - NX - NWQ - NWK; }
  else                               { src = wo; dst = wob;  off = i4 - NX - NWQ - NWK - NWV; }
  float4 v = *reinterpret_cast<const float4*>(src + off);
  ushort4 o;
  o.x = f2bf(v.x); o.y = f2bf(v.y); o.z = f2bf(v.z); o.w = f2bf(v.w);
  *reinterpret_cast<ushort4*>(dst + off) = o;
}

// ------- bf16 MFMA GEMM, LDS-staged 2-phase: C[M][N] = A[M][K] * B[N][K]^T ---
// BK=64, 4 waves (2x2), wave tile (BM/2) x (BN/2).
template<int BM, int BN>
__global__ __launch_bounds__(256) void k_gemm2(
    const unsigned short* __restrict__ A, const unsigned short* __restrict__ B,
    float* __restrict__ C, int N, int K) {
  constexpr int NI = BM / 32;
  constexpr int NJ = BN / 32;
  __shared__ unsigned short As[2][BM * 64];
  __shared__ unsigned short Bs[2][BN * 64];
  const int lane = threadIdx.x & 63;
  const int wave = threadIdx.x >> 6;
  const int wm = wave >> 1, wn = wave & 1;
  const int lr = lane & 15, lk = lane >> 4;
  const int brow = blockIdx.y * BM;
  const int bcol = blockIdx.x * BN;

  const int srow = lane >> 3;
  const int scol = ((lane & 7) ^ srow) * 8;
  const unsigned short* Ag = A + (long)(brow + srow) * K + scol;
  const unsigned short* Bg = B + (long)(bcol + srow) * K + scol;

  f32x4 acc[NI][NJ];
#pragma unroll
  for (int i = 0; i < NI; i++)
#pragma unroll
    for (int j = 0; j < NJ; j++) acc[i][j] = (f32x4){0.f, 0.f, 0.f, 0.f};

  const int swz = (lr & 7) << 4;
  const int nt = K / 64;
  int cur = 0;

#pragma unroll
  for (int i = 0; i < NI; i++) {
    int strip = i * 4 + wave;
    glds16(Ag + (long)strip * 8 * K, (char*)As[0] + strip * 1024);
  }
#pragma unroll
  for (int i = 0; i < NJ; i++) {
    int strip = i * 4 + wave;
    glds16(Bg + (long)strip * 8 * K, (char*)Bs[0] + strip * 1024);
  }
  __syncthreads();

  for (int t = 0; t < nt; t++) {
    if (t + 1 < nt) {
      const int kk = (t + 1) * 64;
#pragma unroll
      for (int i = 0; i < NI; i++) {
        int strip = i * 4 + wave;
        glds16(Ag + (long)strip * 8 * K + kk, (char*)As[cur ^ 1] + strip * 1024);
      }
#pragma unroll
      for (int i = 0; i < NJ; i++) {
        int strip = i * 4 + wave;
        glds16(Bg + (long)strip * 8 * K + kk, (char*)Bs[cur ^ 1] + strip * 1024);
      }
    }
#pragma unroll
    for (int s = 0; s < 2; s++) {
      bf16x8 a[NI], b[NJ];
#pragma unroll
      for (int i = 0; i < NI; i++) {
        int row = wm * (BM / 2) + i * 16 + lr;
        a[i] = *reinterpret_cast<const bf16x8*>(
            (const char*)As[cur] + row * 128 + ((s * 64 + lk * 16) ^ swz));
      }
#pragma unroll
      for (int j = 0; j < NJ; j++) {
        int row = wn * (BN / 2) + j * 16 + lr;
        b[j] = *reinterpret_cast<const bf16x8*>(
            (const char*)Bs[cur] + row * 128 + ((s * 64 + lk * 16) ^ swz));
      }
#pragma unroll
      for (int i = 0; i < NI; i++)
#pragma unroll
        for (int j = 0; j < NJ; j++)
          acc[i][j] = __builtin_amdgcn_mfma_f32_16x16x32_bf16(a[i], b[j], acc[i][j], 0, 0, 0);
    }
    __syncthreads();
    cur ^= 1;
  }

#pragma unroll
  for (int i = 0; i < NI; i++)
#pragma unroll
    for (int j = 0; j < NJ; j++)
#pragma unroll
      for (int p = 0; p < 4; p++)
        C[(long)(brow + wm * (BM / 2) + i * 16 + lk * 4 + p) * N +
          (bcol + wn * (BN / 2) + j * 16 + lr)] = acc[i][j][p];
}

// ---------------- fused RMSNorm + RoPE -> bf16, one wave per (t, head) -------
__global__ void k_norm_rope(const float* __restrict__ qkv_lin,
                            unsigned short* __restrict__ qb, unsigned short* __restrict__ kb,
                            const float* __restrict__ cosT, const float* __restrict__ sinT,
                            const float* __restrict__ qw, const float* __restrict__ kw) {
  int gw = (blockIdx.x * blockDim.x + threadIdx.x) >> 6;
  int lane = threadIdx.x & 63;
  int t = gw / (NH + NKV);
  int hh = gw % (NH + NKV);
  if (t >= T_TOK) return;
  const float* base;
  unsigned short* ob;
  const float* w;
  if (hh < NH) {
    base = qkv_lin + (long)t * 3072 + hh * HD;
    ob   = qb + (long)t * (NH * HD) + hh * HD;
    w = qw;
  } else {
    int kh = hh - NH;
    base = qkv_lin + (long)t * 3072 + 2048 + kh * HD;
    ob   = kb + (long)t * (NKV * HD) + kh * HD;
    w = kw;
  }
  float v = base[lane];
  float ss = v * v;
#pragma unroll
  for (int off = 1; off < 64; off <<= 1) ss += __shfl_xor(ss, off);
  float xn = v * rsqrtf(ss * (1.0f / HD) + 1e-6f) * w[lane];
  float other = __shfl_xor(xn, 32);
  float c = cosT[t * HD + lane], s = sinT[t * HD + lane];
  ob[lane] = f2bf(xn * c + (lane < 32 ? -other : other) * s);
}

// -------- V transpose: qkv_lin cols 2560.. (f32) -> [512][1024] bf16 ---------
__global__ __launch_bounds__(256) void k_vt(const float* __restrict__ qkv_lin,
                                            unsigned short* __restrict__ out) {
  __shared__ float t[32][33];
  int tx = threadIdx.x & 31, ty = threadIdx.x >> 5;
  int r0 = blockIdx.y * 32;
  int c0 = blockIdx.x * 32;
#pragma unroll
  for (int r = 0; r < 4; r++)
    t[ty + r * 8][tx] = qkv_lin[(long)(r0 + ty + r * 8) * 3072 + 2560 + c0 + tx];
  __syncthreads();
#pragma unroll
  for (int r = 0; r < 4; r++)
    out[(long)(c0 + ty + r * 8) * 1024 + r0 + tx] = f2bf(t[tx][ty + r * 8]);
}

// ------ flash attention v3: block = (16-row q block, kvh); 4 waves = 4 heads -
// K/V tiles shared via double-buffered LDS (global_load_lds, XOR-swizzled).
__global__ __launch_bounds__(256) void k_flash(
    const unsigned short* __restrict__ qb, const unsigned short* __restrict__ kb,
    const unsigned short* __restrict__ vtb, unsigned short* __restrict__ ao) {
  __shared__ unsigned short Ks[2][64 * 64];   // [key][d] swizzled, 8 KB each
  __shared__ unsigned short Vs[2][64 * 64];   // [d][key] swizzled
  __shared__ unsigned short plds[4][16 * 64]; // per-wave P strip
  const int rb = 63 - blockIdx.x;   // 16-row q block, longest-first
  const int kvh = blockIdx.y;
  const int lane = threadIdx.x & 63;
  const int wave = threadIdx.x >> 6;
  const int h = kvh * 4 + wave;     // the 4 q-heads sharing this KV head
  const int lr = lane & 15, lk = lane >> 4;
  const int qrow = rb * 16;
  const int qt = rb >> 2;               // diag 64-key tile
  const int qrel = (rb & 3) * 16 + lr;  // row within covering 64-tile
  const int pswz = (lr & 7) << 4;
  char* pbase = (char*)plds[wave];
  const float SC = 0.125f * 1.44269504f;  // 1/sqrt(64) * log2(e)
  const f32x4 z4 = {0.f, 0.f, 0.f, 0.f};

  // staging source pattern (k_gemm2-proven): lane covers row=lane>>3 of an
  // 8-row strip, global col inverse-swizzled so LDS stays linear.
  const int srow = lane >> 3;
  const int scol = ((lane & 7) ^ srow) * 8;

#define STAGE(buf, tt) do {                                                    \
    _Pragma("unroll") for (int s_ = 0; s_ < 2; s_++) {                         \
      int strip = s_ * 4 + wave;                                               \
      glds16(kb + (long)((tt) * 64 + strip * 8 + srow) * 512 + kvh * 64 + scol,\
             (char*)Ks[buf] + strip * 1024);                                   \
      glds16(vtb + (long)(kvh * 64 + strip * 8 + srow) * 1024 + (tt) * 64 + scol,\
             (char*)Vs[buf] + strip * 1024);                                   \
    }                                                                          \
  } while (0)

  const unsigned short* qp = qb + (long)(qrow + lr) * (NH * HD) + h * HD + lk * 8;
  bf16x8 qa0 = *reinterpret_cast<const bf16x8*>(qp);
  bf16x8 qa1 = *reinterpret_cast<const bf16x8*>(qp + 32);

  f32x4 o[4];
#pragma unroll
  for (int f = 0; f < 4; f++) o[f] = z4;
  float m2 = -3.0e38f;  // running max (exp2 domain), lane q-row = lr
  float lp = 0.f;       // lane-partial denominator

  const int ntiles = qt + 1;
  int cur = 0;
  STAGE(0, 0);
  __syncthreads();

  for (int t = 0; t < ntiles; t++) {
    if (t + 1 < ntiles) STAGE(cur ^ 1, t + 1);
    // K fragments from LDS (A-operand of swapped QK^T: lane = key)
    bf16x8 kf0[4], kf1[4];
#pragma unroll
    for (int f = 0; f < 4; f++) {
      const char* kbase = (const char*)Ks[cur] + (f * 16 + lr) * 128;
      kf0[f] = *reinterpret_cast<const bf16x8*>(kbase + ((lk * 16) ^ pswz));
      kf1[f] = *reinterpret_cast<const bf16x8*>(kbase + ((64 + lk * 16) ^ pswz));
    }
    // S^T strip: 64 keys x 16 q
    f32x4 sacc[4];
    __builtin_amdgcn_s_setprio(1);
#pragma unroll
    for (int f = 0; f < 4; f++) {
      sacc[f] = __builtin_amdgcn_mfma_f32_16x16x32_bf16(kf0[f], qa0, z4, 0, 0, 0);
      sacc[f] = __builtin_amdgcn_mfma_f32_16x16x32_bf16(kf1[f], qa1, sacc[f], 0, 0, 0);
    }
    __builtin_amdgcn_s_setprio(0);
    const bool diag = (t == qt);
    float tmax = -3.0e38f;
#pragma unroll
    for (int f = 0; f < 4; f++)
#pragma unroll
      for (int p = 0; p < 4; p++) {
        float s_ = sacc[f][p] * SC;
        if (diag && (f * 16 + lk * 4 + p) > qrel) s_ = -3.0e38f;
        sacc[f][p] = s_;
        tmax = fmaxf(tmax, s_);
      }
    tmax = fmaxf(tmax, __shfl_xor(tmax, 16));
    tmax = fmaxf(tmax, __shfl_xor(tmax, 32));
    float mn = fmaxf(m2, tmax);
    float r = exp2f(m2 - mn);
    m2 = mn;
    float rp[4];
#pragma unroll
    for (int p = 0; p < 4; p++)
      rp[p] = __shfl(r, (lane & 48) | (lk * 4 + p));
    float ps = 0.f;
#pragma unroll
    for (int f = 0; f < 4; f++) {
      float e0 = exp2f(sacc[f][0] - mn), e1 = exp2f(sacc[f][1] - mn);
      float e2 = exp2f(sacc[f][2] - mn), e3 = exp2f(sacc[f][3] - mn);
      ps += (e0 + e1) + (e2 + e3);
      uint2 pk;
      pk.x = (unsigned)f2bf(e0) | ((unsigned)f2bf(e1) << 16);
      pk.y = (unsigned)f2bf(e2) | ((unsigned)f2bf(e3) << 16);
      *reinterpret_cast<uint2*>(pbase + lr * 128 + ((f * 32 + lk * 8) ^ pswz)) = pk;
    }
    lp = lp * r + ps;
#pragma unroll
    for (int fd = 0; fd < 4; fd++)
#pragma unroll
      for (int p = 0; p < 4; p++) o[fd][p] *= rp[p];
    // V fragments from LDS (B-operand of PV: row = d)
    bf16x8 vfr[8];
#pragma unroll
    for (int fd = 0; fd < 4; fd++) {
      const char* vbase = (const char*)Vs[cur] + (fd * 16 + lr) * 128;
      vfr[fd]     = *reinterpret_cast<const bf16x8*>(vbase + ((lk * 16) ^ pswz));
      vfr[4 + fd] = *reinterpret_cast<const bf16x8*>(vbase + ((64 + lk * 16) ^ pswz));
    }
    __builtin_amdgcn_s_setprio(1);
#pragma unroll
    for (int ks = 0; ks < 2; ks++) {
      bf16x8 pa = *reinterpret_cast<const bf16x8*>(
          pbase + lr * 128 + ((ks * 64 + lk * 16) ^ pswz));
#pragma unroll
      for (int fd = 0; fd < 4; fd++)
        o[fd] = __builtin_amdgcn_mfma_f32_16x16x32_bf16(pa, vfr[ks * 4 + fd], o[fd], 0, 0, 0);
    }
    __builtin_amdgcn_s_setprio(0);
    __syncthreads();
    cur ^= 1;
  }

  lp += __shfl_xor(lp, 16);
  lp += __shfl_xor(lp, 32);
  float lo[4];
#pragma unroll
  for (int p = 0; p < 4; p++) lo[p] = __shfl(lp, (lane & 48) | (lk * 4 + p));
#pragma unroll
  for (int fd = 0; fd < 4; fd++)
#pragma unroll
    for (int p = 0; p < 4; p++) {
      int qg = qrow + lk * 4 + p;
      int d = fd * 16 + lr;
      ao[(long)qg * (NH * HD) + h * HD + d] = f2bf(o[fd][p] / lo[p]);
    }
#undef STAGE
}

extern "C" void kernel_launch(void* const* d_in, const int* in_sizes, int n_in,
                              void* d_out, int out_size, void* d_ws, size_t ws_size,
                              hipStream_t stream) {
  const float* x    = (const float*)d_in[0];
  const float* cosT = (const float*)d_in[3];
  const float* sinT = (const float*)d_in[5];
  const float* Wq   = (const float*)d_in[7];
  const float* Wk   = (const float*)d_in[8];
  const float* Wv   = (const float*)d_in[9];
  const float* Wo   = (const float*)d_in[10];
  const float* qw   = (const float*)d_in[11];
  const float* kw   = (const float*)d_in[12];
  float* out = (float*)d_out;

  char* ws = (char*)d_ws;
  unsigned short* xb    = (unsigned short*)(ws);               // 0..4 MB
  unsigned short* Wqkv  = (unsigned short*)(ws + (4u << 20));  // 4..16 MB
  unsigned short* Wob   = (unsigned short*)(ws + (16u << 20)); // 16..24 MB
  float* qkv_lin = (float*)(ws + (24u << 20));                 // 24..36 MB
  unsigned short* qbb = (unsigned short*)(ws + (36u << 20));   // 36..40 MB
  unsigned short* kbb = (unsigned short*)(ws + (40u << 20));   // 40..41 MB
  unsigned short* vtb = (unsigned short*)(ws + (41u << 20));   // 41..42 MB
  unsigned short* ao  = (unsigned short*)(ws + (42u << 20));   // 42..46 MB

  // all fp32 -> bf16 conversions in one launch
  k_cvt_all<<<12288, 256, 0, stream>>>(x, Wq, Wk, Wv, Wo, xb, Wqkv, Wob);

  // fused QKV projection: [1024][3072] = x * Wqkv^T  (192 blocks, 128x128)
  k_gemm2<128, 128><<<dim3(24, 8), 256, 0, stream>>>(xb, Wqkv, qkv_lin, 3072, 2048);

  // RMSNorm + RoPE -> bf16 q/k
  k_norm_rope<<<(T_TOK * (NH + NKV) * 64) / 256, 256, 0, stream>>>(
      qkv_lin, qbb, kbb, cosT, sinT, qw, kw);

  // V^T bf16 for PV B-operand
  k_vt<<<dim3(16, 32), 256, 0, stream>>>(qkv_lin, vtb);

  // flash attention -> bf16 [T][H*HD]  (512 blocks x 4 waves, KV shared)
  k_flash<<<dim3(64, 8), 256, 0, stream>>>(qbb, kbb, vtb, ao);

  // output projection -> fp32 d_out  (128 blocks, 128x128)
  k_gemm2<128, 128><<<dim3(16, 8), 256, 0, stream>>>(ao, Wob, out, 2048, 2048);
}

// Round 10
// 218.903 us; speedup vs baseline: 1.2974x; 1.0080x over previous
//
#include <hip/hip_runtime.h>

typedef __bf16 bf16x8 __attribute__((ext_vector_type(8)));
typedef float f32x4 __attribute__((ext_vector_type(4)));

#define T_TOK 1024
#define DIN   2048
#define NH    32
#define NKV   8
#define HD    64

__device__ __forceinline__ unsigned short f2bf(float f) {
  unsigned int u = __float_as_uint(f);
  unsigned int r = (u + 0x7fffu + ((u >> 16) & 1u)) >> 16;
  return (unsigned short)r;
}

__device__ __forceinline__ void glds16(const void* g, void* lds) {
  __builtin_amdgcn_global_load_lds(
      (const __attribute__((address_space(1))) void*)g,
      (__attribute__((address_space(3))) void*)lds, 16, 0, 0);
}

// ------------- fused fp32 -> bf16 convert for all 5 operands, 1 launch -------
__global__ __launch_bounds__(256) void k_cvt_all(
    const float* __restrict__ x,  const float* __restrict__ wq,
    const float* __restrict__ wk, const float* __restrict__ wv,
    const float* __restrict__ wo, unsigned short* __restrict__ xb,
    unsigned short* __restrict__ wqkv, unsigned short* __restrict__ wob) {
  const long NX = 1l << 21, NWQ = 1l << 22, NWK = 1l << 20, NWV = 1l << 20;
  long i4 = ((long)blockIdx.x * blockDim.x + threadIdx.x) * 4;
  const float* src;
  unsigned short* dst;
  long off;
  if (i4 < NX)                       { src = x;  dst = xb;   off = i4; }
  else if (i4 < NX + NWQ)            { src = wq; dst = wqkv; off = i4 - NX; }
  else if (i4 < NX + NWQ + NWK)      { src = wk; dst = wqkv + NWQ; off = i4 - NX - NWQ; }
  else if (i4 < NX + NWQ + NWK + NWV){ src = wv; dst = wqkv + NWQ + NWK; off = i4 - NX - NWQ - NWK; }
  else                               { src = wo; dst = wob;  off = i4 - NX - NWQ - NWK - NWV; }
  float4 v = *reinterpret_cast<const float4*>(src + off);
  ushort4 o;
  o.x = f2bf(v.x); o.y = f2bf(v.y); o.z = f2bf(v.z); o.w = f2bf(v.w);
  *reinterpret_cast<ushort4*>(dst + off) = o;
}

// ---- bf16 MFMA GEMM, 4-deep pipelined (counted vmcnt, T3+T4): C = A * B^T ---
// BK=64, 4 waves (2x2), wave tile (BM/2) x (BN/2). Batch = 8 glds16/wave.
template<int BM, int BN>
__global__ __launch_bounds__(256) void k_gemm3(
    const unsigned short* __restrict__ A, const unsigned short* __restrict__ B,
    float* __restrict__ C, int N, int K) {
  constexpr int NI = BM / 32;
  constexpr int NJ = BN / 32;
  __shared__ unsigned short As[4][BM * 64];
  __shared__ unsigned short Bs[4][BN * 64];
  const int lane = threadIdx.x & 63;
  const int wave = threadIdx.x >> 6;
  const int wm = wave >> 1, wn = wave & 1;
  const int lr = lane & 15, lk = lane >> 4;
  const int brow = blockIdx.y * BM;
  const int bcol = blockIdx.x * BN;

  const int srow = lane >> 3;
  const int scol = ((lane & 7) ^ srow) * 8;
  const unsigned short* Ag = A + (long)(brow + srow) * K + scol;
  const unsigned short* Bg = B + (long)(bcol + srow) * K + scol;

  f32x4 acc[NI][NJ];
#pragma unroll
  for (int i = 0; i < NI; i++)
#pragma unroll
    for (int j = 0; j < NJ; j++) acc[i][j] = (f32x4){0.f, 0.f, 0.f, 0.f};

  const int swz = (lr & 7) << 4;
  const int nt = K / 64;

#define GSTAGE(buf, tt) do {                                                   \
    const int kk_ = (tt) * 64;                                                 \
    _Pragma("unroll") for (int i_ = 0; i_ < NI; i_++) {                        \
      int strip = i_ * 4 + wave;                                               \
      glds16(Ag + (long)strip * 8 * K + kk_, (char*)As[buf] + strip * 1024);   \
    }                                                                          \
    _Pragma("unroll") for (int i_ = 0; i_ < NJ; i_++) {                        \
      int strip = i_ * 4 + wave;                                               \
      glds16(Bg + (long)strip * 8 * K + kk_, (char*)Bs[buf] + strip * 1024);   \
    }                                                                          \
  } while (0)

  // prologue: 3 batches in flight (24 loads/wave outstanding)
  GSTAGE(0, 0);
  GSTAGE(1, 1);
  GSTAGE(2, 2);

  for (int t = 0; t < nt; t++) {
    // wait for batch t only; keep up to 2 batches (16 loads) in flight
    if (t + 2 < nt)      { asm volatile("s_waitcnt vmcnt(16)" ::: "memory"); }
    else if (t + 1 < nt) { asm volatile("s_waitcnt vmcnt(8)"  ::: "memory"); }
    else                 { asm volatile("s_waitcnt vmcnt(0)"  ::: "memory"); }
    __builtin_amdgcn_sched_barrier(0);
    __builtin_amdgcn_s_barrier();
    if (t + 3 < nt) GSTAGE((t + 3) & 3, t + 3);
    const int cur = t & 3;
#pragma unroll
    for (int s = 0; s < 2; s++) {
      bf16x8 a[NI], b[NJ];
#pragma unroll
      for (int i = 0; i < NI; i++) {
        int row = wm * (BM / 2) + i * 16 + lr;
        a[i] = *reinterpret_cast<const bf16x8*>(
            (const char*)As[cur] + row * 128 + ((s * 64 + lk * 16) ^ swz));
      }
#pragma unroll
      for (int j = 0; j < NJ; j++) {
        int row = wn * (BN / 2) + j * 16 + lr;
        b[j] = *reinterpret_cast<const bf16x8*>(
            (const char*)Bs[cur] + row * 128 + ((s * 64 + lk * 16) ^ swz));
      }
      __builtin_amdgcn_s_setprio(1);
#pragma unroll
      for (int i = 0; i < NI; i++)
#pragma unroll
        for (int j = 0; j < NJ; j++)
          acc[i][j] = __builtin_amdgcn_mfma_f32_16x16x32_bf16(a[i], b[j], acc[i][j], 0, 0, 0);
      __builtin_amdgcn_s_setprio(0);
    }
  }
#undef GSTAGE

#pragma unroll
  for (int i = 0; i < NI; i++)
#pragma unroll
    for (int j = 0; j < NJ; j++)
#pragma unroll
      for (int p = 0; p < 4; p++)
        C[(long)(brow + wm * (BM / 2) + i * 16 + lk * 4 + p) * N +
          (bcol + wn * (BN / 2) + j * 16 + lr)] = acc[i][j][p];
}

// ---------------- fused RMSNorm + RoPE -> bf16, one wave per (t, head) -------
__global__ void k_norm_rope(const float* __restrict__ qkv_lin,
                            unsigned short* __restrict__ qb, unsigned short* __restrict__ kb,
                            const float* __restrict__ cosT, const float* __restrict__ sinT,
                            const float* __restrict__ qw, const float* __restrict__ kw) {
  int gw = (blockIdx.x * blockDim.x + threadIdx.x) >> 6;
  int lane = threadIdx.x & 63;
  int t = gw / (NH + NKV);
  int hh = gw % (NH + NKV);
  if (t >= T_TOK) return;
  const float* base;
  unsigned short* ob;
  const float* w;
  if (hh < NH) {
    base = qkv_lin + (long)t * 3072 + hh * HD;
    ob   = qb + (long)t * (NH * HD) + hh * HD;
    w = qw;
  } else {
    int kh = hh - NH;
    base = qkv_lin + (long)t * 3072 + 2048 + kh * HD;
    ob   = kb + (long)t * (NKV * HD) + kh * HD;
    w = kw;
  }
  float v = base[lane];
  float ss = v * v;
#pragma unroll
  for (int off = 1; off < 64; off <<= 1) ss += __shfl_xor(ss, off);
  float xn = v * rsqrtf(ss * (1.0f / HD) + 1e-6f) * w[lane];
  float other = __shfl_xor(xn, 32);
  float c = cosT[t * HD + lane], s = sinT[t * HD + lane];
  ob[lane] = f2bf(xn * c + (lane < 32 ? -other : other) * s);
}

// -------- V transpose: qkv_lin cols 2560.. (f32) -> [512][1024] bf16 ---------
__global__ __launch_bounds__(256) void k_vt(const float* __restrict__ qkv_lin,
                                            unsigned short* __restrict__ out) {
  __shared__ float t[32][33];
  int tx = threadIdx.x & 31, ty = threadIdx.x >> 5;
  int r0 = blockIdx.y * 32;
  int c0 = blockIdx.x * 32;
#pragma unroll
  for (int r = 0; r < 4; r++)
    t[ty + r * 8][tx] = qkv_lin[(long)(r0 + ty + r * 8) * 3072 + 2560 + c0 + tx];
  __syncthreads();
#pragma unroll
  for (int r = 0; r < 4; r++)
    out[(long)(c0 + ty + r * 8) * 1024 + r0 + tx] = f2bf(t[tx][ty + r * 8]);
}

// ------ flash attention v4: block = (16-row q block, kvh); 4 waves = 4 heads -
// K/V shared via 4-deep pipelined LDS (counted vmcnt, raw barriers).
__global__ __launch_bounds__(256) void k_flash(
    const unsigned short* __restrict__ qb, const unsigned short* __restrict__ kb,
    const unsigned short* __restrict__ vtb, unsigned short* __restrict__ ao) {
  __shared__ unsigned short Ks[4][64 * 64];   // [key][d] swizzled, 8 KB each
  __shared__ unsigned short Vs[4][64 * 64];   // [d][key] swizzled
  __shared__ unsigned short plds[4][16 * 64]; // per-wave P strip
  const int rb = 63 - blockIdx.x;   // 16-row q block, longest-first
  const int kvh = blockIdx.y;
  const int lane = threadIdx.x & 63;
  const int wave = threadIdx.x >> 6;
  const int h = kvh * 4 + wave;     // the 4 q-heads sharing this KV head
  const int lr = lane & 15, lk = lane >> 4;
  const int qrow = rb * 16;
  const int qt = rb >> 2;               // diag 64-key tile
  const int qrel = (rb & 3) * 16 + lr;  // row within covering 64-tile
  const int pswz = (lr & 7) << 4;
  char* pbase = (char*)plds[wave];
  const float SC = 0.125f * 1.44269504f;  // 1/sqrt(64) * log2(e)
  const f32x4 z4 = {0.f, 0.f, 0.f, 0.f};

  const int srow = lane >> 3;
  const int scol = ((lane & 7) ^ srow) * 8;

#define STAGE(buf, tt) do {                                                    \
    _Pragma("unroll") for (int s_ = 0; s_ < 2; s_++) {                         \
      int strip = s_ * 4 + wave;                                               \
      glds16(kb + (long)((tt) * 64 + strip * 8 + srow) * 512 + kvh * 64 + scol,\
             (char*)Ks[buf] + strip * 1024);                                   \
      glds16(vtb + (long)(kvh * 64 + strip * 8 + srow) * 1024 + (tt) * 64 + scol,\
             (char*)Vs[buf] + strip * 1024);                                   \
    }                                                                          \
  } while (0)

  const unsigned short* qp = qb + (long)(qrow + lr) * (NH * HD) + h * HD + lk * 8;
  bf16x8 qa0 = *reinterpret_cast<const bf16x8*>(qp);
  bf16x8 qa1 = *reinterpret_cast<const bf16x8*>(qp + 32);

  f32x4 o[4];
#pragma unroll
  for (int f = 0; f < 4; f++) o[f] = z4;
  float m2 = -3.0e38f;  // running max (exp2 domain), lane q-row = lr
  float lp = 0.f;       // lane-partial denominator

  const int ntiles = qt + 1;
  // prologue: up to 3 batches (4 loads/wave each) in flight
  STAGE(0, 0);
  if (ntiles > 1) STAGE(1, 1);
  if (ntiles > 2) STAGE(2, 2);

  for (int t = 0; t < ntiles; t++) {
    if (t + 2 < ntiles)      { asm volatile("s_waitcnt vmcnt(8)" ::: "memory"); }
    else if (t + 1 < ntiles) { asm volatile("s_waitcnt vmcnt(4)" ::: "memory"); }
    else                     { asm volatile("s_waitcnt vmcnt(0)" ::: "memory"); }
    __builtin_amdgcn_sched_barrier(0);
    __builtin_amdgcn_s_barrier();
    if (t + 3 < ntiles) STAGE((t + 3) & 3, t + 3);
    const int cur = t & 3;
    // K fragments from LDS (A-operand of swapped QK^T: lane = key)
    bf16x8 kf0[4], kf1[4];
#pragma unroll
    for (int f = 0; f < 4; f++) {
      const char* kbase = (const char*)Ks[cur] + (f * 16 + lr) * 128;
      kf0[f] = *reinterpret_cast<const bf16x8*>(kbase + ((lk * 16) ^ pswz));
      kf1[f] = *reinterpret_cast<const bf16x8*>(kbase + ((64 + lk * 16) ^ pswz));
    }
    f32x4 sacc[4];
    __builtin_amdgcn_s_setprio(1);
#pragma unroll
    for (int f = 0; f < 4; f++) {
      sacc[f] = __builtin_amdgcn_mfma_f32_16x16x32_bf16(kf0[f], qa0, z4, 0, 0, 0);
      sacc[f] = __builtin_amdgcn_mfma_f32_16x16x32_bf16(kf1[f], qa1, sacc[f], 0, 0, 0);
    }
    __builtin_amdgcn_s_setprio(0);
    const bool diag = (t == qt);
    float tmax = -3.0e38f;
#pragma unroll
    for (int f = 0; f < 4; f++)
#pragma unroll
      for (int p = 0; p < 4; p++) {
        float s_ = sacc[f][p] * SC;
        if (diag && (f * 16 + lk * 4 + p) > qrel) s_ = -3.0e38f;
        sacc[f][p] = s_;
        tmax = fmaxf(tmax, s_);
      }
    tmax = fmaxf(tmax, __shfl_xor(tmax, 16));
    tmax = fmaxf(tmax, __shfl_xor(tmax, 32));
    float mn = fmaxf(m2, tmax);
    float r = exp2f(m2 - mn);
    m2 = mn;
    float rp[4];
#pragma unroll
    for (int p = 0; p < 4; p++)
      rp[p] = __shfl(r, (lane & 48) | (lk * 4 + p));
    float ps = 0.f;
#pragma unroll
    for (int f = 0; f < 4; f++) {
      float e0 = exp2f(sacc[f][0] - mn), e1 = exp2f(sacc[f][1] - mn);
      float e2 = exp2f(sacc[f][2] - mn), e3 = exp2f(sacc[f][3] - mn);
      ps += (e0 + e1) + (e2 + e3);
      uint2 pk;
      pk.x = (unsigned)f2bf(e0) | ((unsigned)f2bf(e1) << 16);
      pk.y = (unsigned)f2bf(e2) | ((unsigned)f2bf(e3) << 16);
      *reinterpret_cast<uint2*>(pbase + lr * 128 + ((f * 32 + lk * 8) ^ pswz)) = pk;
    }
    lp = lp * r + ps;
#pragma unroll
    for (int fd = 0; fd < 4; fd++)
#pragma unroll
      for (int p = 0; p < 4; p++) o[fd][p] *= rp[p];
    // V fragments from LDS (B-operand of PV: row = d)
    bf16x8 vfr[8];
#pragma unroll
    for (int fd = 0; fd < 4; fd++) {
      const char* vbase = (const char*)Vs[cur] + (fd * 16 + lr) * 128;
      vfr[fd]     = *reinterpret_cast<const bf16x8*>(vbase + ((lk * 16) ^ pswz));
      vfr[4 + fd] = *reinterpret_cast<const bf16x8*>(vbase + ((64 + lk * 16) ^ pswz));
    }
    __builtin_amdgcn_s_setprio(1);
#pragma unroll
    for (int ks = 0; ks < 2; ks++) {
      bf16x8 pa = *reinterpret_cast<const bf16x8*>(
          pbase + lr * 128 + ((ks * 64 + lk * 16) ^ pswz));
#pragma unroll
      for (int fd = 0; fd < 4; fd++)
        o[fd] = __builtin_amdgcn_mfma_f32_16x16x32_bf16(pa, vfr[ks * 4 + fd], o[fd], 0, 0, 0);
    }
    __builtin_amdgcn_s_setprio(0);
  }
#undef STAGE

  lp += __shfl_xor(lp, 16);
  lp += __shfl_xor(lp, 32);
  float lo[4];
#pragma unroll
  for (int p = 0; p < 4; p++) lo[p] = __shfl(lp, (lane & 48) | (lk * 4 + p));
#pragma unroll
  for (int fd = 0; fd < 4; fd++)
#pragma unroll
    for (int p = 0; p < 4; p++) {
      int qg = qrow + lk * 4 + p;
      int d = fd * 16 + lr;
      ao[(long)qg * (NH * HD) + h * HD + d] = f2bf(o[fd][p] / lo[p]);
    }
}

extern "C" void kernel_launch(void* const* d_in, const int* in_sizes, int n_in,
                              void* d_out, int out_size, void* d_ws, size_t ws_size,
                              hipStream_t stream) {
  const float* x    = (const float*)d_in[0];
  const float* cosT = (const float*)d_in[3];
  const float* sinT = (const float*)d_in[5];
  const float* Wq   = (const float*)d_in[7];
  const float* Wk   = (const float*)d_in[8];
  const float* Wv   = (const float*)d_in[9];
  const float* Wo   = (const float*)d_in[10];
  const float* qw   = (const float*)d_in[11];
  const float* kw   = (const float*)d_in[12];
  float* out = (float*)d_out;

  char* ws = (char*)d_ws;
  unsigned short* xb    = (unsigned short*)(ws);               // 0..4 MB
  unsigned short* Wqkv  = (unsigned short*)(ws + (4u << 20));  // 4..16 MB
  unsigned short* Wob   = (unsigned short*)(ws + (16u << 20)); // 16..24 MB
  float* qkv_lin = (float*)(ws + (24u << 20));                 // 24..36 MB
  unsigned short* qbb = (unsigned short*)(ws + (36u << 20));   // 36..40 MB
  unsigned short* kbb = (unsigned short*)(ws + (40u << 20));   // 40..41 MB
  unsigned short* vtb = (unsigned short*)(ws + (41u << 20));   // 41..42 MB
  unsigned short* ao  = (unsigned short*)(ws + (42u << 20));   // 42..46 MB

  // all fp32 -> bf16 conversions in one launch
  k_cvt_all<<<12288, 256, 0, stream>>>(x, Wq, Wk, Wv, Wo, xb, Wqkv, Wob);

  // fused QKV projection: [1024][3072] = x * Wqkv^T  (192 blocks, 128x128)
  k_gemm3<128, 128><<<dim3(24, 8), 256, 0, stream>>>(xb, Wqkv, qkv_lin, 3072, 2048);

  // RMSNorm + RoPE -> bf16 q/k
  k_norm_rope<<<(T_TOK * (NH + NKV) * 64) / 256, 256, 0, stream>>>(
      qkv_lin, qbb, kbb, cosT, sinT, qw, kw);

  // V^T bf16 for PV B-operand
  k_vt<<<dim3(16, 32), 256, 0, stream>>>(qkv_lin, vtb);

  // flash attention -> bf16 [T][H*HD]  (512 blocks x 4 waves, KV shared)
  k_flash<<<dim3(64, 8), 256, 0, stream>>>(qbb, kbb, vtb, ao);

  // output projection -> fp32 d_out  (128 blocks, 128x128)
  k_gemm3<128, 128><<<dim3(16, 8), 256, 0, stream>>>(ao, Wob, out, 2048, 2048);
}

// Round 11
// 199.348 us; speedup vs baseline: 1.4247x; 1.0981x over previous
//
#include <hip/hip_runtime.h>

typedef __bf16 bf16x8 __attribute__((ext_vector_type(8)));
typedef float f32x4 __attribute__((ext_vector_type(4)));

#define T_TOK 1024
#define DIN   2048
#define NH    32
#define NKV   8
#define HD    64

__device__ __forceinline__ unsigned short f2bf(float f) {
  unsigned int u = __float_as_uint(f);
  unsigned int r = (u + 0x7fffu + ((u >> 16) & 1u)) >> 16;
  return (unsigned short)r;
}

__device__ __forceinline__ void glds16(const void* g, void* lds) {
  __builtin_amdgcn_global_load_lds(
      (const __attribute__((address_space(1))) void*)g,
      (__attribute__((address_space(3))) void*)lds, 16, 0, 0);
}

// ------------- fused fp32 -> bf16 convert for all 5 operands, 1 launch -------
__global__ __launch_bounds__(256) void k_cvt_all(
    const float* __restrict__ x,  const float* __restrict__ wq,
    const float* __restrict__ wk, const float* __restrict__ wv,
    const float* __restrict__ wo, unsigned short* __restrict__ xb,
    unsigned short* __restrict__ wqkv, unsigned short* __restrict__ wob) {
  const long NX = 1l << 21, NWQ = 1l << 22, NWK = 1l << 20, NWV = 1l << 20;
  long i4 = ((long)blockIdx.x * blockDim.x + threadIdx.x) * 4;
  const float* src;
  unsigned short* dst;
  long off;
  if (i4 < NX)                       { src = x;  dst = xb;   off = i4; }
  else if (i4 < NX + NWQ)            { src = wq; dst = wqkv; off = i4 - NX; }
  else if (i4 < NX + NWQ + NWK)      { src = wk; dst = wqkv + NWQ; off = i4 - NX - NWQ; }
  else if (i4 < NX + NWQ + NWK + NWV){ src = wv; dst = wqkv + NWQ + NWK; off = i4 - NX - NWQ - NWK; }
  else                               { src = wo; dst = wob;  off = i4 - NX - NWQ - NWK - NWV; }
  float4 v = *reinterpret_cast<const float4*>(src + off);
  ushort4 o;
  o.x = f2bf(v.x); o.y = f2bf(v.y); o.z = f2bf(v.z); o.w = f2bf(v.w);
  *reinterpret_cast<ushort4*>(dst + off) = o;
}

// ---- bf16 MFMA GEMM, 3-deep pipelined (counted vmcnt): C = A * B^T ----------
// BM=64 BN=128 BK=64, 4 waves (2x2), wave tile 32x64 (head-aligned).
// MODE 0: plain f32 C store. MODE 1: fused RMSNorm+RoPE (q/k) + V^T epilogue.
template<int BM, int BN, int MODE>
__global__ __launch_bounds__(256) void k_gemm3(
    const unsigned short* __restrict__ A, const unsigned short* __restrict__ B,
    float* __restrict__ C, int N, int K,
    unsigned short* __restrict__ qb, unsigned short* __restrict__ kbo,
    unsigned short* __restrict__ vtb, const float* __restrict__ cosT,
    const float* __restrict__ sinT, const float* __restrict__ qw,
    const float* __restrict__ kw) {
  constexpr int NI = BM / 32;
  constexpr int NJ = BN / 32;
  static_assert(NI + NJ == 6, "vmcnt literals assume 6 loads/batch/wave");
  __shared__ unsigned short As[3][BM * 64];
  __shared__ unsigned short Bs[3][BN * 64];
  const int lane = threadIdx.x & 63;
  const int wave = threadIdx.x >> 6;
  const int wm = wave >> 1, wn = wave & 1;
  const int lr = lane & 15, lk = lane >> 4;
  const int brow = blockIdx.y * BM;
  const int bcol = blockIdx.x * BN;

  const int srow = lane >> 3;
  const int scol = ((lane & 7) ^ srow) * 8;
  const unsigned short* Ag = A + (long)(brow + srow) * K + scol;
  const unsigned short* Bg = B + (long)(bcol + srow) * K + scol;

  f32x4 acc[NI][NJ];
#pragma unroll
  for (int i = 0; i < NI; i++)
#pragma unroll
    for (int j = 0; j < NJ; j++) acc[i][j] = (f32x4){0.f, 0.f, 0.f, 0.f};

  const int swz = (lr & 7) << 4;
  const int nt = K / 64;

#define GSTAGE(buf, tt) do {                                                   \
    const int kk_ = (tt) * 64;                                                 \
    _Pragma("unroll") for (int i_ = 0; i_ < NI; i_++) {                        \
      int strip = i_ * 4 + wave;                                               \
      glds16(Ag + (long)strip * 8 * K + kk_, (char*)As[buf] + strip * 1024);   \
    }                                                                          \
    _Pragma("unroll") for (int i_ = 0; i_ < NJ; i_++) {                        \
      int strip = i_ * 4 + wave;                                               \
      glds16(Bg + (long)strip * 8 * K + kk_, (char*)Bs[buf] + strip * 1024);   \
    }                                                                          \
  } while (0)

  GSTAGE(0, 0);
  GSTAGE(1, 1);

  for (int t = 0; t < nt; t++) {
    if (t + 1 < nt) { asm volatile("s_waitcnt vmcnt(6)" ::: "memory"); }
    else            { asm volatile("s_waitcnt vmcnt(0)" ::: "memory"); }
    __builtin_amdgcn_sched_barrier(0);
    __builtin_amdgcn_s_barrier();
    if (t + 2 < nt) GSTAGE((t + 2) % 3, t + 2);
    const int cur = t % 3;
#pragma unroll
    for (int s = 0; s < 2; s++) {
      bf16x8 a[NI], b[NJ];
#pragma unroll
      for (int i = 0; i < NI; i++) {
        int row = wm * (BM / 2) + i * 16 + lr;
        a[i] = *reinterpret_cast<const bf16x8*>(
            (const char*)As[cur] + row * 128 + ((s * 64 + lk * 16) ^ swz));
      }
#pragma unroll
      for (int j = 0; j < NJ; j++) {
        int row = wn * (BN / 2) + j * 16 + lr;
        b[j] = *reinterpret_cast<const bf16x8*>(
            (const char*)Bs[cur] + row * 128 + ((s * 64 + lk * 16) ^ swz));
      }
      __builtin_amdgcn_s_setprio(1);
#pragma unroll
      for (int i = 0; i < NI; i++)
#pragma unroll
        for (int j = 0; j < NJ; j++)
          acc[i][j] = __builtin_amdgcn_mfma_f32_16x16x32_bf16(a[i], b[j], acc[i][j], 0, 0, 0);
      __builtin_amdgcn_s_setprio(0);
    }
  }
#undef GSTAGE

  if constexpr (MODE == 1) {
    // fused epilogue: wave's 64-col span = one head (BN/2 == HD)
    const int colbase = bcol + wn * 64;
    if (colbase < 2560) {  // q or k head: RMSNorm + RoPE -> bf16
      const bool isQ = (colbase < 2048);
      const float* w = isQ ? qw : kw;
      unsigned short* dst = isQ ? qb : kbo;
      const int dN = isQ ? (NH * HD) : (NKV * HD);
      const int dcol = isQ ? colbase : colbase - 2048;
      float wv[NJ];
#pragma unroll
      for (int j = 0; j < NJ; j++) wv[j] = w[j * 16 + lr];
#pragma unroll
      for (int i = 0; i < NI; i++) {
#pragma unroll
        for (int p = 0; p < 4; p++) {
          float s2 = 0.f;
#pragma unroll
          for (int j = 0; j < NJ; j++) s2 += acc[i][j][p] * acc[i][j][p];
          s2 += __shfl_xor(s2, 1);
          s2 += __shfl_xor(s2, 2);
          s2 += __shfl_xor(s2, 4);
          s2 += __shfl_xor(s2, 8);
          const float inv = rsqrtf(s2 * (1.0f / HD) + 1e-6f);
          const int t = brow + wm * (BM / 2) + i * 16 + lk * 4 + p;
#pragma unroll
          for (int j = 0; j < NJ; j++) {
            const int hd = j * 16 + lr;
            const float xn = acc[i][j][p] * inv * wv[j];
            const int jp = (j < 2) ? j + 2 : j - 2;
            float rot = acc[i][jp][p] * inv * wv[jp];
            if (j < 2) rot = -rot;
            const float c = cosT[t * HD + hd], s = sinT[t * HD + hd];
            dst[(long)t * dN + dcol + hd] = f2bf(xn * c + rot * s);
          }
        }
      }
    } else {  // v head: bf16, transposed into vtb[512][1024]
#pragma unroll
      for (int i = 0; i < NI; i++) {
        const int t0 = brow + wm * (BM / 2) + i * 16 + lk * 4;
#pragma unroll
        for (int j = 0; j < NJ; j++) {
          const int c = colbase - 2560 + j * 16 + lr;
          ushort4 pk;
          pk.x = f2bf(acc[i][j][0]);
          pk.y = f2bf(acc[i][j][1]);
          pk.z = f2bf(acc[i][j][2]);
          pk.w = f2bf(acc[i][j][3]);
          *reinterpret_cast<ushort4*>(vtb + (long)c * T_TOK + t0) = pk;
        }
      }
    }
  } else {
#pragma unroll
    for (int i = 0; i < NI; i++)
#pragma unroll
      for (int j = 0; j < NJ; j++)
#pragma unroll
        for (int p = 0; p < 4; p++)
          C[(long)(brow + wm * (BM / 2) + i * 16 + lk * 4 + p) * N +
            (bcol + wn * (BN / 2) + j * 16 + lr)] = acc[i][j][p];
  }
}

// ------ flash attention v4: block = (16-row q block, kvh); 4 waves = 4 heads -
// K/V shared via 4-deep pipelined LDS (counted vmcnt, raw barriers).
__global__ __launch_bounds__(256) void k_flash(
    const unsigned short* __restrict__ qb, const unsigned short* __restrict__ kb,
    const unsigned short* __restrict__ vtb, unsigned short* __restrict__ ao) {
  __shared__ unsigned short Ks[4][64 * 64];   // [key][d] swizzled, 8 KB each
  __shared__ unsigned short Vs[4][64 * 64];   // [d][key] swizzled
  __shared__ unsigned short plds[4][16 * 64]; // per-wave P strip
  const int rb = 63 - blockIdx.x;   // 16-row q block, longest-first
  const int kvh = blockIdx.y;
  const int lane = threadIdx.x & 63;
  const int wave = threadIdx.x >> 6;
  const int h = kvh * 4 + wave;     // the 4 q-heads sharing this KV head
  const int lr = lane & 15, lk = lane >> 4;
  const int qrow = rb * 16;
  const int qt = rb >> 2;               // diag 64-key tile
  const int qrel = (rb & 3) * 16 + lr;  // row within covering 64-tile
  const int pswz = (lr & 7) << 4;
  char* pbase = (char*)plds[wave];
  const float SC = 0.125f * 1.44269504f;  // 1/sqrt(64) * log2(e)
  const f32x4 z4 = {0.f, 0.f, 0.f, 0.f};

  const int srow = lane >> 3;
  const int scol = ((lane & 7) ^ srow) * 8;

#define STAGE(buf, tt) do {                                                    \
    _Pragma("unroll") for (int s_ = 0; s_ < 2; s_++) {                         \
      int strip = s_ * 4 + wave;                                               \
      glds16(kb + (long)((tt) * 64 + strip * 8 + srow) * 512 + kvh * 64 + scol,\
             (char*)Ks[buf] + strip * 1024);                                   \
      glds16(vtb + (long)(kvh * 64 + strip * 8 + srow) * 1024 + (tt) * 64 + scol,\
             (char*)Vs[buf] + strip * 1024);                                   \
    }                                                                          \
  } while (0)

  const unsigned short* qp = qb + (long)(qrow + lr) * (NH * HD) + h * HD + lk * 8;
  bf16x8 qa0 = *reinterpret_cast<const bf16x8*>(qp);
  bf16x8 qa1 = *reinterpret_cast<const bf16x8*>(qp + 32);

  f32x4 o[4];
#pragma unroll
  for (int f = 0; f < 4; f++) o[f] = z4;
  float m2 = -3.0e38f;  // running max (exp2 domain), lane q-row = lr
  float lp = 0.f;       // lane-partial denominator

  const int ntiles = qt + 1;
  STAGE(0, 0);
  if (ntiles > 1) STAGE(1, 1);
  if (ntiles > 2) STAGE(2, 2);

  for (int t = 0; t < ntiles; t++) {
    if (t + 2 < ntiles)      { asm volatile("s_waitcnt vmcnt(8)" ::: "memory"); }
    else if (t + 1 < ntiles) { asm volatile("s_waitcnt vmcnt(4)" ::: "memory"); }
    else                     { asm volatile("s_waitcnt vmcnt(0)" ::: "memory"); }
    __builtin_amdgcn_sched_barrier(0);
    __builtin_amdgcn_s_barrier();
    if (t + 3 < ntiles) STAGE((t + 3) & 3, t + 3);
    const int cur = t & 3;
    bf16x8 kf0[4], kf1[4];
#pragma unroll
    for (int f = 0; f < 4; f++) {
      const char* kbase = (const char*)Ks[cur] + (f * 16 + lr) * 128;
      kf0[f] = *reinterpret_cast<const bf16x8*>(kbase + ((lk * 16) ^ pswz));
      kf1[f] = *reinterpret_cast<const bf16x8*>(kbase + ((64 + lk * 16) ^ pswz));
    }
    f32x4 sacc[4];
    __builtin_amdgcn_s_setprio(1);
#pragma unroll
    for (int f = 0; f < 4; f++) {
      sacc[f] = __builtin_amdgcn_mfma_f32_16x16x32_bf16(kf0[f], qa0, z4, 0, 0, 0);
      sacc[f] = __builtin_amdgcn_mfma_f32_16x16x32_bf16(kf1[f], qa1, sacc[f], 0, 0, 0);
    }
    __builtin_amdgcn_s_setprio(0);
    const bool diag = (t == qt);
    float tmax = -3.0e38f;
#pragma unroll
    for (int f = 0; f < 4; f++)
#pragma unroll
      for (int p = 0; p < 4; p++) {
        float s_ = sacc[f][p] * SC;
        if (diag && (f * 16 + lk * 4 + p) > qrel) s_ = -3.0e38f;
        sacc[f][p] = s_;
        tmax = fmaxf(tmax, s_);
      }
    tmax = fmaxf(tmax, __shfl_xor(tmax, 16));
    tmax = fmaxf(tmax, __shfl_xor(tmax, 32));
    float mn = fmaxf(m2, tmax);
    float r = exp2f(m2 - mn);
    m2 = mn;
    float rp[4];
#pragma unroll
    for (int p = 0; p < 4; p++)
      rp[p] = __shfl(r, (lane & 48) | (lk * 4 + p));
    float ps = 0.f;
#pragma unroll
    for (int f = 0; f < 4; f++) {
      float e0 = exp2f(sacc[f][0] - mn), e1 = exp2f(sacc[f][1] - mn);
      float e2 = exp2f(sacc[f][2] - mn), e3 = exp2f(sacc[f][3] - mn);
      ps += (e0 + e1) + (e2 + e3);
      uint2 pk;
      pk.x = (unsigned)f2bf(e0) | ((unsigned)f2bf(e1) << 16);
      pk.y = (unsigned)f2bf(e2) | ((unsigned)f2bf(e3) << 16);
      *reinterpret_cast<uint2*>(pbase + lr * 128 + ((f * 32 + lk * 8) ^ pswz)) = pk;
    }
    lp = lp * r + ps;
#pragma unroll
    for (int fd = 0; fd < 4; fd++)
#pragma unroll
      for (int p = 0; p < 4; p++) o[fd][p] *= rp[p];
    bf16x8 vfr[8];
#pragma unroll
    for (int fd = 0; fd < 4; fd++) {
      const char* vbase = (const char*)Vs[cur] + (fd * 16 + lr) * 128;
      vfr[fd]     = *reinterpret_cast<const bf16x8*>(vbase + ((lk * 16) ^ pswz));
      vfr[4 + fd] = *reinterpret_cast<const bf16x8*>(vbase + ((64 + lk * 16) ^ pswz));
    }
    __builtin_amdgcn_s_setprio(1);
#pragma unroll
    for (int ks = 0; ks < 2; ks++) {
      bf16x8 pa = *reinterpret_cast<const bf16x8*>(
          pbase + lr * 128 + ((ks * 64 + lk * 16) ^ pswz));
#pragma unroll
      for (int fd = 0; fd < 4; fd++)
        o[fd] = __builtin_amdgcn_mfma_f32_16x16x32_bf16(pa, vfr[ks * 4 + fd], o[fd], 0, 0, 0);
    }
    __builtin_amdgcn_s_setprio(0);
  }
#undef STAGE

  lp += __shfl_xor(lp, 16);
  lp += __shfl_xor(lp, 32);
  float lo[4];
#pragma unroll
  for (int p = 0; p < 4; p++) lo[p] = __shfl(lp, (lane & 48) | (lk * 4 + p));
#pragma unroll
  for (int fd = 0; fd < 4; fd++)
#pragma unroll
    for (int p = 0; p < 4; p++) {
      int qg = qrow + lk * 4 + p;
      int d = fd * 16 + lr;
      ao[(long)qg * (NH * HD) + h * HD + d] = f2bf(o[fd][p] / lo[p]);
    }
}

extern "C" void kernel_launch(void* const* d_in, const int* in_sizes, int n_in,
                              void* d_out, int out_size, void* d_ws, size_t ws_size,
                              hipStream_t stream) {
  const float* x    = (const float*)d_in[0];
  const float* cosT = (const float*)d_in[3];
  const float* sinT = (const float*)d_in[5];
  const float* Wq   = (const float*)d_in[7];
  const float* Wk   = (const float*)d_in[8];
  const float* Wv   = (const float*)d_in[9];
  const float* Wo   = (const float*)d_in[10];
  const float* qw   = (const float*)d_in[11];
  const float* kw   = (const float*)d_in[12];
  float* out = (float*)d_out;

  char* ws = (char*)d_ws;
  unsigned short* xb    = (unsigned short*)(ws);               // 0..4 MB
  unsigned short* Wqkv  = (unsigned short*)(ws + (4u << 20));  // 4..16 MB
  unsigned short* Wob   = (unsigned short*)(ws + (16u << 20)); // 16..24 MB
  unsigned short* qbb = (unsigned short*)(ws + (24u << 20));   // 24..28 MB
  unsigned short* kbb = (unsigned short*)(ws + (28u << 20));   // 28..29 MB
  unsigned short* vtb = (unsigned short*)(ws + (29u << 20));   // 29..30 MB
  unsigned short* ao  = (unsigned short*)(ws + (30u << 20));   // 30..34 MB

  // all fp32 -> bf16 conversions in one launch
  k_cvt_all<<<12288, 256, 0, stream>>>(x, Wq, Wk, Wv, Wo, xb, Wqkv, Wob);

  // fused QKV projection + RMSNorm + RoPE + V^T  (384 blocks, 2/CU)
  k_gemm3<64, 128, 1><<<dim3(24, 16), 256, 0, stream>>>(
      xb, Wqkv, nullptr, 3072, 2048, qbb, kbb, vtb, cosT, sinT, qw, kw);

  // flash attention -> bf16 [T][H*HD]  (512 blocks x 4 waves, KV shared)
  k_flash<<<dim3(64, 8), 256, 0, stream>>>(qbb, kbb, vtb, ao);

  // output projection -> fp32 d_out  (256 blocks, 1/CU)
  k_gemm3<64, 128, 0><<<dim3(16, 16), 256, 0, stream>>>(
      ao, Wob, out, 2048, 2048, nullptr, nullptr, nullptr, nullptr, nullptr,
      nullptr, nullptr);
}

// Round 13
// 194.602 us; speedup vs baseline: 1.4594x; 1.0244x over previous
//
#include <hip/hip_runtime.h>

typedef __bf16 bf16x8 __attribute__((ext_vector_type(8)));
typedef float f32x4 __attribute__((ext_vector_type(4)));

#define T_TOK 1024
#define DIN   2048
#define NH    32
#define NKV   8
#define HD    64

__device__ __forceinline__ unsigned short f2bf(float f) {
  unsigned int u = __float_as_uint(f);
  unsigned int r = (u + 0x7fffu + ((u >> 16) & 1u)) >> 16;
  return (unsigned short)r;
}

__device__ __forceinline__ void glds16(const void* g, void* lds) {
  __builtin_amdgcn_global_load_lds(
      (const __attribute__((address_space(1))) void*)g,
      (__attribute__((address_space(3))) void*)lds, 16, 0, 0);
}

// ------------- fused fp32 -> bf16 convert for all 5 operands, 1 launch -------
__global__ __launch_bounds__(256) void k_cvt_all(
    const float* __restrict__ x,  const float* __restrict__ wq,
    const float* __restrict__ wk, const float* __restrict__ wv,
    const float* __restrict__ wo, unsigned short* __restrict__ xb,
    unsigned short* __restrict__ wqkv, unsigned short* __restrict__ wob) {
  const long NX = 1l << 21, NWQ = 1l << 22, NWK = 1l << 20, NWV = 1l << 20;
  long i4 = ((long)blockIdx.x * blockDim.x + threadIdx.x) * 4;
  const float* src;
  unsigned short* dst;
  long off;
  if (i4 < NX)                       { src = x;  dst = xb;   off = i4; }
  else if (i4 < NX + NWQ)            { src = wq; dst = wqkv; off = i4 - NX; }
  else if (i4 < NX + NWQ + NWK)      { src = wk; dst = wqkv + NWQ; off = i4 - NX - NWQ; }
  else if (i4 < NX + NWQ + NWK + NWV){ src = wv; dst = wqkv + NWQ + NWK; off = i4 - NX - NWQ - NWK; }
  else                               { src = wo; dst = wob;  off = i4 - NX - NWQ - NWK - NWV; }
  float4 v = *reinterpret_cast<const float4*>(src + off);
  ushort4 o;
  o.x = f2bf(v.x); o.y = f2bf(v.y); o.z = f2bf(v.z); o.w = f2bf(v.w);
  *reinterpret_cast<ushort4*>(dst + off) = o;
}

// ---- bf16 MFMA GEMM, 3-deep pipelined (counted vmcnt): C = A * B^T ----------
// BM=64 BN=128 BK=64, 4 waves (2x2), wave tile 32x64 (head-aligned).
// XCD-chunked block remap: each XCD owns gridDim.x/8 contiguous col tiles.
// MODE 0: plain f32 C store. MODE 1: fused RMSNorm+RoPE (q/k) + V^T epilogue.
template<int BM, int BN, int MODE>
__global__ __launch_bounds__(256) void k_gemm3(
    const unsigned short* __restrict__ A, const unsigned short* __restrict__ B,
    float* __restrict__ C, int N, int K,
    unsigned short* __restrict__ qb, unsigned short* __restrict__ kbo,
    unsigned short* __restrict__ vtb, const float* __restrict__ cosT,
    const float* __restrict__ sinT, const float* __restrict__ qw,
    const float* __restrict__ kw) {
  constexpr int NI = BM / 32;
  constexpr int NJ = BN / 32;
  static_assert(NI + NJ == 6, "vmcnt literals assume 6 loads/batch/wave");
  __shared__ unsigned short As[3][BM * 64];
  __shared__ unsigned short Bs[3][BN * 64];
  const int lane = threadIdx.x & 63;
  const int wave = threadIdx.x >> 6;
  const int wm = wave >> 1, wn = wave & 1;
  const int lr = lane & 15, lk = lane >> 4;

  // XCD-chunked remap (requires gridDim.x % 8 == 0; bijective)
  const int lin = blockIdx.x + blockIdx.y * gridDim.x;
  const int cpx = gridDim.x >> 3;          // col tiles per XCD
  const int xcd = lin & 7;
  const int idx = lin >> 3;
  const int bx  = xcd * cpx + idx % cpx;
  const int by  = idx / cpx;
  const int brow = by * BM;
  const int bcol = bx * BN;

  const int srow = lane >> 3;
  const int scol = ((lane & 7) ^ srow) * 8;
  const unsigned short* Ag = A + (long)(brow + srow) * K + scol;
  const unsigned short* Bg = B + (long)(bcol + srow) * K + scol;

  f32x4 acc[NI][NJ];
#pragma unroll
  for (int i = 0; i < NI; i++)
#pragma unroll
    for (int j = 0; j < NJ; j++) acc[i][j] = (f32x4){0.f, 0.f, 0.f, 0.f};

  const int swz = (lr & 7) << 4;
  const int nt = K / 64;

#define GSTAGE(buf, tt) do {                                                   \
    const int kk_ = (tt) * 64;                                                 \
    _Pragma("unroll") for (int i_ = 0; i_ < NI; i_++) {                        \
      int strip = i_ * 4 + wave;                                               \
      glds16(Ag + (long)strip * 8 * K + kk_, (char*)As[buf] + strip * 1024);   \
    }                                                                          \
    _Pragma("unroll") for (int i_ = 0; i_ < NJ; i_++) {                        \
      int strip = i_ * 4 + wave;                                               \
      glds16(Bg + (long)strip * 8 * K + kk_, (char*)Bs[buf] + strip * 1024);   \
    }                                                                          \
  } while (0)

  GSTAGE(0, 0);
  GSTAGE(1, 1);

  for (int t = 0; t < nt; t++) {
    if (t + 1 < nt) { asm volatile("s_waitcnt vmcnt(6)" ::: "memory"); }
    else            { asm volatile("s_waitcnt vmcnt(0)" ::: "memory"); }
    __builtin_amdgcn_sched_barrier(0);
    __builtin_amdgcn_s_barrier();
    if (t + 2 < nt) GSTAGE((t + 2) % 3, t + 2);
    const int cur = t % 3;
#pragma unroll
    for (int s = 0; s < 2; s++) {
      bf16x8 a[NI], b[NJ];
#pragma unroll
      for (int i = 0; i < NI; i++) {
        int row = wm * (BM / 2) + i * 16 + lr;
        a[i] = *reinterpret_cast<const bf16x8*>(
            (const char*)As[cur] + row * 128 + ((s * 64 + lk * 16) ^ swz));
      }
#pragma unroll
      for (int j = 0; j < NJ; j++) {
        int row = wn * (BN / 2) + j * 16 + lr;
        b[j] = *reinterpret_cast<const bf16x8*>(
            (const char*)Bs[cur] + row * 128 + ((s * 64 + lk * 16) ^ swz));
      }
      __builtin_amdgcn_s_setprio(1);
#pragma unroll
      for (int i = 0; i < NI; i++)
#pragma unroll
        for (int j = 0; j < NJ; j++)
          acc[i][j] = __builtin_amdgcn_mfma_f32_16x16x32_bf16(a[i], b[j], acc[i][j], 0, 0, 0);
      __builtin_amdgcn_s_setprio(0);
    }
  }
#undef GSTAGE

  if constexpr (MODE == 1) {
    // fused epilogue: wave's 64-col span = one head (BN/2 == HD)
    const int colbase = bcol + wn * 64;
    if (colbase < 2560) {  // q or k head: RMSNorm + RoPE -> bf16
      const bool isQ = (colbase < 2048);
      const float* w = isQ ? qw : kw;
      unsigned short* dst = isQ ? qb : kbo;
      const int dN = isQ ? (NH * HD) : (NKV * HD);
      const int dcol = isQ ? colbase : colbase - 2048;
      float wv[NJ];
#pragma unroll
      for (int j = 0; j < NJ; j++) wv[j] = w[j * 16 + lr];
#pragma unroll
      for (int i = 0; i < NI; i++) {
#pragma unroll
        for (int p = 0; p < 4; p++) {
          float s2 = 0.f;
#pragma unroll
          for (int j = 0; j < NJ; j++) s2 += acc[i][j][p] * acc[i][j][p];
          s2 += __shfl_xor(s2, 1);
          s2 += __shfl_xor(s2, 2);
          s2 += __shfl_xor(s2, 4);
          s2 += __shfl_xor(s2, 8);
          const float inv = rsqrtf(s2 * (1.0f / HD) + 1e-6f);
          const int t = brow + wm * (BM / 2) + i * 16 + lk * 4 + p;
#pragma unroll
          for (int j = 0; j < NJ; j++) {
            const int hd = j * 16 + lr;
            const float xn = acc[i][j][p] * inv * wv[j];
            const int jp = (j < 2) ? j + 2 : j - 2;
            float rot = acc[i][jp][p] * inv * wv[jp];
            if (j < 2) rot = -rot;
            const float c = cosT[t * HD + hd], s = sinT[t * HD + hd];
            dst[(long)t * dN + dcol + hd] = f2bf(xn * c + rot * s);
          }
        }
      }
    } else {  // v head: bf16, transposed into vtb[512][1024]
#pragma unroll
      for (int i = 0; i < NI; i++) {
        const int t0 = brow + wm * (BM / 2) + i * 16 + lk * 4;
#pragma unroll
        for (int j = 0; j < NJ; j++) {
          const int c = colbase - 2560 + j * 16 + lr;
          ushort4 pk;
          pk.x = f2bf(acc[i][j][0]);
          pk.y = f2bf(acc[i][j][1]);
          pk.z = f2bf(acc[i][j][2]);
          pk.w = f2bf(acc[i][j][3]);
          *reinterpret_cast<ushort4*>(vtb + (long)c * T_TOK + t0) = pk;
        }
      }
    }
  } else {
#pragma unroll
    for (int i = 0; i < NI; i++)
#pragma unroll
      for (int j = 0; j < NJ; j++)
#pragma unroll
        for (int p = 0; p < 4; p++)
          C[(long)(brow + wm * (BM / 2) + i * 16 + lk * 4 + p) * N +
            (bcol + wn * (BN / 2) + j * 16 + lr)] = acc[i][j][p];
  }
}

// ------ flash attention v4: block = (16-row q block, kvh); 4 waves = 4 heads -
// K/V shared via 4-deep pipelined LDS (counted vmcnt, raw barriers).
// XCD remap: kvh = lin&7 pins each KV head's K/V/Q working set to one XCD L2.
__global__ __launch_bounds__(256) void k_flash(
    const unsigned short* __restrict__ qb, const unsigned short* __restrict__ kb,
    const unsigned short* __restrict__ vtb, unsigned short* __restrict__ ao) {
  __shared__ unsigned short Ks[4][64 * 64];   // [key][d] swizzled, 8 KB each
  __shared__ unsigned short Vs[4][64 * 64];   // [d][key] swizzled
  __shared__ unsigned short plds[4][16 * 64]; // per-wave P strip
  const int lin = blockIdx.x + blockIdx.y * gridDim.x;  // 0..511
  const int kvh = lin & 7;          // KV head -> XCD (round-robin model)
  const int rb  = 63 - (lin >> 3);  // 16-row q block, longest-first per XCD
  const int lane = threadIdx.x & 63;
  const int wave = threadIdx.x >> 6;
  const int h = kvh * 4 + wave;     // the 4 q-heads sharing this KV head
  const int lr = lane & 15, lk = lane >> 4;
  const int qrow = rb * 16;
  const int qt = rb >> 2;               // diag 64-key tile
  const int qrel = (rb & 3) * 16 + lr;  // row within covering 64-tile
  const int pswz = (lr & 7) << 4;
  char* pbase = (char*)plds[wave];
  const float SC = 0.125f * 1.44269504f;  // 1/sqrt(64) * log2(e)
  const f32x4 z4 = {0.f, 0.f, 0.f, 0.f};

  const int srow = lane >> 3;
  const int scol = ((lane & 7) ^ srow) * 8;

#define STAGE(buf, tt) do {                                                    \
    _Pragma("unroll") for (int s_ = 0; s_ < 2; s_++) {                         \
      int strip = s_ * 4 + wave;                                               \
      glds16(kb + (long)((tt) * 64 + strip * 8 + srow) * 512 + kvh * 64 + scol,\
             (char*)Ks[buf] + strip * 1024);                                   \
      glds16(vtb + (long)(kvh * 64 + strip * 8 + srow) * 1024 + (tt) * 64 + scol,\
             (char*)Vs[buf] + strip * 1024);                                   \
    }                                                                          \
  } while (0)

  const unsigned short* qp = qb + (long)(qrow + lr) * (NH * HD) + h * HD + lk * 8;
  bf16x8 qa0 = *reinterpret_cast<const bf16x8*>(qp);
  bf16x8 qa1 = *reinterpret_cast<const bf16x8*>(qp + 32);

  f32x4 o[4];
#pragma unroll
  for (int f = 0; f < 4; f++) o[f] = z4;
  float m2 = -3.0e38f;  // running max (exp2 domain), lane q-row = lr
  float lp = 0.f;       // lane-partial denominator

  const int ntiles = qt + 1;
  STAGE(0, 0);
  if (ntiles > 1) STAGE(1, 1);
  if (ntiles > 2) STAGE(2, 2);

  for (int t = 0; t < ntiles; t++) {
    if (t + 2 < ntiles)      { asm volatile("s_waitcnt vmcnt(8)" ::: "memory"); }
    else if (t + 1 < ntiles) { asm volatile("s_waitcnt vmcnt(4)" ::: "memory"); }
    else                     { asm volatile("s_waitcnt vmcnt(0)" ::: "memory"); }
    __builtin_amdgcn_sched_barrier(0);
    __builtin_amdgcn_s_barrier();
    if (t + 3 < ntiles) STAGE((t + 3) & 3, t + 3);
    const int cur = t & 3;
    bf16x8 kf0[4], kf1[4];
#pragma unroll
    for (int f = 0; f < 4; f++) {
      const char* kbase = (const char*)Ks[cur] + (f * 16 + lr) * 128;
      kf0[f] = *reinterpret_cast<const bf16x8*>(kbase + ((lk * 16) ^ pswz));
      kf1[f] = *reinterpret_cast<const bf16x8*>(kbase + ((64 + lk * 16) ^ pswz));
    }
    f32x4 sacc[4];
    __builtin_amdgcn_s_setprio(1);
#pragma unroll
    for (int f = 0; f < 4; f++) {
      sacc[f] = __builtin_amdgcn_mfma_f32_16x16x32_bf16(kf0[f], qa0, z4, 0, 0, 0);
      sacc[f] = __builtin_amdgcn_mfma_f32_16x16x32_bf16(kf1[f], qa1, sacc[f], 0, 0, 0);
    }
    __builtin_amdgcn_s_setprio(0);
    const bool diag = (t == qt);
    float tmax = -3.0e38f;
#pragma unroll
    for (int f = 0; f < 4; f++)
#pragma unroll
      for (int p = 0; p < 4; p++) {
        float s_ = sacc[f][p] * SC;
        if (diag && (f * 16 + lk * 4 + p) > qrel) s_ = -3.0e38f;
        sacc[f][p] = s_;
        tmax = fmaxf(tmax, s_);
      }
    tmax = fmaxf(tmax, __shfl_xor(tmax, 16));
    tmax = fmaxf(tmax, __shfl_xor(tmax, 32));
    float mn = fmaxf(m2, tmax);
    float r = exp2f(m2 - mn);
    m2 = mn;
    float rp[4];
#pragma unroll
    for (int p = 0; p < 4; p++)
      rp[p] = __shfl(r, (lane & 48) | (lk * 4 + p));
    float ps = 0.f;
#pragma unroll
    for (int f = 0; f < 4; f++) {
      float e0 = exp2f(sacc[f][0] - mn), e1 = exp2f(sacc[f][1] - mn);
      float e2 = exp2f(sacc[f][2] - mn), e3 = exp2f(sacc[f][3] - mn);
      ps += (e0 + e1) + (e2 + e3);
      uint2 pk;
      pk.x = (unsigned)f2bf(e0) | ((unsigned)f2bf(e1) << 16);
      pk.y = (unsigned)f2bf(e2) | ((unsigned)f2bf(e3) << 16);
      *reinterpret_cast<uint2*>(pbase + lr * 128 + ((f * 32 + lk * 8) ^ pswz)) = pk;
    }
    lp = lp * r + ps;
#pragma unroll
    for (int fd = 0; fd < 4; fd++)
#pragma unroll
      for (int p = 0; p < 4; p++) o[fd][p] *= rp[p];
    bf16x8 vfr[8];
#pragma unroll
    for (int fd = 0; fd < 4; fd++) {
      const char* vbase = (const char*)Vs[cur] + (fd * 16 + lr) * 128;
      vfr[fd]     = *reinterpret_cast<const bf16x8*>(vbase + ((lk * 16) ^ pswz));
      vfr[4 + fd] = *reinterpret_cast<const bf16x8*>(vbase + ((64 + lk * 16) ^ pswz));
    }
    __builtin_amdgcn_s_setprio(1);
#pragma unroll
    for (int ks = 0; ks < 2; ks++) {
      bf16x8 pa = *reinterpret_cast<const bf16x8*>(
          pbase + lr * 128 + ((ks * 64 + lk * 16) ^ pswz));
#pragma unroll
      for (int fd = 0; fd < 4; fd++)
        o[fd] = __builtin_amdgcn_mfma_f32_16x16x32_bf16(pa, vfr[ks * 4 + fd], o[fd], 0, 0, 0);
    }
    __builtin_amdgcn_s_setprio(0);
  }
#undef STAGE

  lp += __shfl_xor(lp, 16);
  lp += __shfl_xor(lp, 32);
  float lo[4];
#pragma unroll
  for (int p = 0; p < 4; p++) lo[p] = __shfl(lp, (lane & 48) | (lk * 4 + p));
#pragma unroll
  for (int fd = 0; fd < 4; fd++)
#pragma unroll
    for (int p = 0; p < 4; p++) {
      int qg = qrow + lk * 4 + p;
      int d = fd * 16 + lr;
      ao[(long)qg * (NH * HD) + h * HD + d] = f2bf(o[fd][p] / lo[p]);
    }
}

extern "C" void kernel_launch(void* const* d_in, const int* in_sizes, int n_in,
                              void* d_out, int out_size, void* d_ws, size_t ws_size,
                              hipStream_t stream) {
  const float* x    = (const float*)d_in[0];
  const float* cosT = (const float*)d_in[3];
  const float* sinT = (const float*)d_in[5];
  const float* Wq   = (const float*)d_in[7];
  const float* Wk   = (const float*)d_in[8];
  const float* Wv   = (const float*)d_in[9];
  const float* Wo   = (const float*)d_in[10];
  const float* qw   = (const float*)d_in[11];
  const float* kw   = (const float*)d_in[12];
  float* out = (float*)d_out;

  char* ws = (char*)d_ws;
  unsigned short* xb    = (unsigned short*)(ws);               // 0..4 MB
  unsigned short* Wqkv  = (unsigned short*)(ws + (4u << 20));  // 4..16 MB
  unsigned short* Wob   = (unsigned short*)(ws + (16u << 20)); // 16..24 MB
  unsigned short* qbb = (unsigned short*)(ws + (24u << 20));   // 24..28 MB
  unsigned short* kbb = (unsigned short*)(ws + (28u << 20));   // 28..29 MB
  unsigned short* vtb = (unsigned short*)(ws + (29u << 20));   // 29..30 MB
  unsigned short* ao  = (unsigned short*)(ws + (30u << 20));   // 30..34 MB

  // all fp32 -> bf16 conversions in one launch
  k_cvt_all<<<12288, 256, 0, stream>>>(x, Wq, Wk, Wv, Wo, xb, Wqkv, Wob);

  // fused QKV projection + RMSNorm + RoPE + V^T  (384 blocks, 2/CU)
  k_gemm3<64, 128, 1><<<dim3(24, 16), 256, 0, stream>>>(
      xb, Wqkv, nullptr, 3072, 2048, qbb, kbb, vtb, cosT, sinT, qw, kw);

  // flash attention -> bf16 [T][H*HD]  (512 blocks x 4 waves, KV shared)
  k_flash<<<dim3(64, 8), 256, 0, stream>>>(qbb, kbb, vtb, ao);

  // output projection -> fp32 d_out  (256 blocks, 1/CU)
  k_gemm3<64, 128, 0><<<dim3(16, 16), 256, 0, stream>>>(
      ao, Wob, out, 2048, 2048, nullptr, nullptr, nullptr, nullptr, nullptr,
      nullptr, nullptr);
}